// Round 8
// baseline (162.922 us; speedup 1.0000x reference)
//
#include <hip/hip_runtime.h>
#include <hip/hip_bf16.h>

// N = 50000 nodes, E = 1.6M edges, D_IN = 128, H = 2 heads, C = 32 (HC=64).
// 4 dispatches (R19 = R18 + direct fp8->f16 cvt in attn dot phase):
//   k_prep:  W fp32 -> f16 MFMA-B-frag layout; block 0 zeroes bucketCnt.
//   k_fused: 512-thread blocks. [blocks < cb] partition 4096 edges/block by
//            dst>>8 into padded bucket regions (int4 edge loads, rank-from-
//            histogram, wave-shfl scan); [rest] ELU + 4 GEMMs via MFMA f16,
//            TB=64 nodes/block, 8 waves = 2 per matrix split by row-half.
//   k_build: ONE 1024-thread block per bucket: rank-from-histogram counting
//            sort entirely in regs+LDS, coalesced dump -> srcs16 + row_ptr.
//   k_attn:  wave-per-node softmax, fp8 KV gathers, batched V phase (R14);
//            dot phase uses v_cvt_pk_f16_fp8 (gfx950): 4 ops per K-word
//            instead of 6 (fp8->f16 exact, drops the lossy pkrtz).
// History: R10 L2-capacity bound => fp8 KV (R11: attn 56->47); R13 4B V
// gather 48->43; R14 batched V phase (attn ~35); R15 partition-first +
// rank-trick; R16 direct-atomic CSR REGRESSED 2x (WRITE_SIZE 40->146MB,
// write-allocate on 1.6M random 2B stores); R17 1-block k_build (165.4);
// R18 TB=64 GEMM + int4 partition loads (162.1). R19 (this round): attn
// dot-phase direct fp8->f16 cvt, -33% dot-phase VALU.
// NOTE: dur_us includes ~88us of harness 256MiB workspace fills (2/iter,
// top-5 is all fills); controllable kernel budget is ~74us.

#define DIN 128
#define HC  64
#define EPB 4096        // edges per partition block
#define CAPB 12288      // padded bucket capacity (mean 8163, sigma ~90)

typedef _Float16 h2 __attribute__((ext_vector_type(2)));
typedef _Float16 h4 __attribute__((ext_vector_type(4)));
typedef _Float16 h8 __attribute__((ext_vector_type(8)));
typedef float    f4 __attribute__((ext_vector_type(4)));
typedef float    f2v __attribute__((ext_vector_type(2)));

#if defined(__has_builtin)
#if __has_builtin(__builtin_amdgcn_fdot2)
#define HAVE_FDOT2 1
#endif
#if __has_builtin(__builtin_amdgcn_cvt_pk_f16_fp8)
#define HAVE_PKF16FP8 1
#endif
#endif

static __device__ __forceinline__ float fdot2(h2 a, h2 b, float c) {
#ifdef HAVE_FDOT2
    return __builtin_amdgcn_fdot2(a, b, c, false);
#else
    return fmaf((float)a.x, (float)b.x, fmaf((float)a.y, (float)b.y, c));
#endif
}

// ---------------- prep: W fp32 -> f16 in MFMA B-fragment layout ----------------
__global__ __launch_bounds__(256) void k_prep(
        const float* __restrict__ Wq, const float* __restrict__ Wk,
        const float* __restrict__ Wv, const float* __restrict__ Ws,
        _Float16* __restrict__ Wh, int* __restrict__ bucketCnt) {
    int t = threadIdx.x;
    if (blockIdx.x == 0) bucketCnt[t] = 0;
    int idx = blockIdx.x * 256 + t;   // 0 .. 32767
    int m    = idx >> 13;
    int rem  = idx & 8191;
    int grp  = rem >> 9;          // ks*4 + nt
    int ks   = grp >> 2;
    int nt   = grp & 3;
    int r3   = rem & 511;
    int lane = r3 >> 3;
    int j    = r3 & 7;
    int k = ks * 32 + (lane >> 4) * 8 + j;
    int n = nt * 16 + (lane & 15);
    const float* W = (m == 0) ? Wq : (m == 1) ? Wk : (m == 2) ? Wv : Ws;
    Wh[idx] = (_Float16)W[k * 64 + n];
}

// ---------------- fused: edge partition (first) + MFMA GEMM (TB=64) ----------
#define TB 64
#define XS 136   // f16 stride per node row (128 + 8 pad)
__global__ __launch_bounds__(512) void k_fused(
        const float4* __restrict__ x4,
        const _Float16* __restrict__ Wh,
        const float* __restrict__ bq, const float* __restrict__ bk,
        const float* __restrict__ bv, const float* __restrict__ bs,
        _Float16* __restrict__ Q, unsigned char* __restrict__ KV8,
        float* __restrict__ OUT, int N,
        const int* __restrict__ ei, int* __restrict__ bucketCnt,
        unsigned int* __restrict__ part, int E, int cb) {
    __shared__ alignas(16) char smem[4096 + EPB * 4];   // 20.5 KB (GEMM uses 17.4)
    int t = threadIdx.x;
    int lane = t & 63, wid = t >> 6;

    if ((int)blockIdx.x < cb) {
        // ---------------- partition role (longest jobs -> dispatched first) ----
        int* hist  = (int*)smem;          // 256: counts (atomic rank source)
        int* lbase = hist + 256;          // 256: exclusive prefix
        int* gbase = lbase + 256;         // 256: global run base
        int* wsum  = gbase + 256;         // 4: wave sums for the scan
        unsigned int* stg = (unsigned int*)(smem + 4096);

        int e0 = (int)blockIdx.x * EPB;
        int cnt = min(EPB, E - e0);
        if (t < 256) hist[t] = 0;
        __syncthreads();

        // pass 1: pack + histogram; atomic return value IS the in-bucket rank.
        // Full blocks: int4 loads (4 edges each, 2 per thread).
        unsigned int pk[EPB / 512];
        unsigned short rk[EPB / 512];
        if (cnt == EPB) {
            const int4* s4 = (const int4*)(ei + e0);
            const int4* d4 = (const int4*)(ei + E + e0);
            #pragma unroll
            for (int u = 0; u < EPB / 2048; ++u) {
                int vi = t + u * 512;
                int4 sv = s4[vi];
                int4 dv = d4[vi];
                unsigned int* p = &pk[u * 4];
                p[0] = ((unsigned)dv.x << 16) | (unsigned)sv.x;
                p[1] = ((unsigned)dv.y << 16) | (unsigned)sv.y;
                p[2] = ((unsigned)dv.z << 16) | (unsigned)sv.z;
                p[3] = ((unsigned)dv.w << 16) | (unsigned)sv.w;
                #pragma unroll
                for (int q = 0; q < 4; ++q)
                    rk[u * 4 + q] = (unsigned short)atomicAdd(&hist[p[q] >> 24], 1);
            }
        } else {
            #pragma unroll
            for (int u = 0; u < EPB / 512; ++u) {
                int i = t + u * 512;
                if (i < cnt) {
                    unsigned int d = (unsigned int)ei[E + e0 + i];
                    unsigned int s = (unsigned int)ei[e0 + i];
                    pk[u] = (d << 16) | s;
                    rk[u] = (unsigned short)atomicAdd(&hist[d >> 8], 1);
                }
            }
        }
        __syncthreads();

        // 256-entry exclusive scan (waves 0-3) + bucket-region reservation
        if (t < 256) {
            int v = hist[t];
            int x = v;
            #pragma unroll
            for (int off = 1; off < 64; off <<= 1) {
                int y = __shfl_up(x, off, 64);
                if (lane >= off) x += y;
            }
            if (lane == 63) wsum[wid] = x;
            lbase[t] = x - v;             // wave-local exclusive part
        }
        __syncthreads();
        if (t < 256) {
            int wpre = 0;
            #pragma unroll
            for (int w = 0; w < 4; ++w) wpre += (w < wid) ? wsum[w] : 0;
            lbase[t] += wpre;
            int v = hist[t];
            if (v > 0) {
                int base = atomicAdd(&bucketCnt[t], v);
                base = min(base, CAPB - v);   // clamp: never cross bucket region
                gbase[t] = t * CAPB + base;
            }
        }
        __syncthreads();

        // scatter straight to LDS staging via rank (no second atomic pass)
        if (cnt == EPB) {
            #pragma unroll
            for (int u = 0; u < EPB / 512; ++u)
                stg[lbase[pk[u] >> 24] + (int)rk[u]] = pk[u];
        } else {
            #pragma unroll
            for (int u = 0; u < EPB / 512; ++u) {
                int i = t + u * 512;
                if (i < cnt) stg[lbase[pk[u] >> 24] + (int)rk[u]] = pk[u];
            }
        }
        __syncthreads();
        // contiguous dump per bucket run
        for (int i = t; i < cnt; i += 512) {
            unsigned int pkv = stg[i];
            int b = pkv >> 24;
            part[gbase[b] + (i - lbase[b])] = pkv;
        }
        return;
    }

    // ---------------- GEMM role (MFMA f16, 64 nodes/block, 8 waves) ----------
    _Float16* xs = (_Float16*)smem;   // [64][XS]
    int n0 = ((int)blockIdx.x - cb) * TB;

    #pragma unroll
    for (int u = 0; u < 4; ++u) {
        int idx = t + u * 512;        // 0..2047
        int row = idx >> 5;           // 0..63
        int k4  = idx & 31;
        int node = n0 + row;
        float4 v = make_float4(0.f, 0.f, 0.f, 0.f);
        if (node < N) v = x4[(size_t)node * 32 + k4];
        v.x = (v.x > 0.f) ? v.x : (__expf(v.x) - 1.0f);
        v.y = (v.y > 0.f) ? v.y : (__expf(v.y) - 1.0f);
        v.z = (v.z > 0.f) ? v.z : (__expf(v.z) - 1.0f);
        v.w = (v.w > 0.f) ? v.w : (__expf(v.w) - 1.0f);
        h4 hv = { (_Float16)v.x, (_Float16)v.y, (_Float16)v.z, (_Float16)v.w };
        *(h4*)&xs[row * XS + k4 * 4] = hv;
    }
    __syncthreads();

    int m    = wid >> 1;         // which matrix (wave-uniform)
    int half = wid & 1;          // row-half [0,2)
    int lr   = lane & 15;
    int lq   = lane >> 4;
    int r0   = half * 32;        // this wave's row base inside the tile

    const _Float16* Wm = Wh + m * 8192;
    const float* bias = (m == 0) ? bq : (m == 1) ? bk : (m == 2) ? bv : bs;

    f4 acc[2][4];
    #pragma unroll
    for (int mt = 0; mt < 2; ++mt)
        #pragma unroll
        for (int nt = 0; nt < 4; ++nt)
            acc[mt][nt] = (f4){0.f, 0.f, 0.f, 0.f};

    #pragma unroll
    for (int ks = 0; ks < 4; ++ks) {
        h8 a0 = *(const h8*)&xs[(r0 + lr) * XS + ks * 32 + lq * 8];
        h8 a1 = *(const h8*)&xs[(r0 + 16 + lr) * XS + ks * 32 + lq * 8];
        #pragma unroll
        for (int nt = 0; nt < 4; ++nt) {
            h8 b = *(const h8*)&Wm[((ks * 4 + nt) << 9) + lane * 8];
            acc[0][nt] = __builtin_amdgcn_mfma_f32_16x16x32_f16(a0, b, acc[0][nt], 0, 0, 0);
            acc[1][nt] = __builtin_amdgcn_mfma_f32_16x16x32_f16(a1, b, acc[1][nt], 0, 0, 0);
        }
    }

    // epilogue: D lane mapping col = lane&15, row = (lane>>4)*4 + reg
    #pragma unroll
    for (int nt = 0; nt < 4; ++nt) {
        int col = nt * 16 + lr;
        float bb = bias[col];
        #pragma unroll
        for (int mt = 0; mt < 2; ++mt) {
            #pragma unroll
            for (int r = 0; r < 4; ++r) {
                int node = n0 + r0 + mt * 16 + lq * 4 + r;
                if (node < N) {
                    float val = acc[mt][nt][r] + bb;
                    if (m == 3) {
                        OUT[((size_t)node << 6) + col] = val;
                    } else if (m == 0) {
                        Q[((size_t)node << 6) + col] = (_Float16)val;
                    } else {
                        // K -> row bytes [0,64), V -> [64,128)
                        int pk8 = __builtin_amdgcn_cvt_pk_fp8_f32(val, val, 0, false);
                        KV8[((size_t)node << 7) + ((m == 2) ? 64 : 0) + col] =
                            (unsigned char)(pk8 & 0xFF);
                    }
                }
            }
        }
    }
}

// ---------------- build: one 1024-thread block per bucket ----------------
// Counting sort of one bucket (<=CAPB edges) with the rank-from-histogram
// trick: one part read per edge (12/thread in regs), one 256-scan, LDS
// scatter, coalesced dump.
__global__ __launch_bounds__(1024) void k_build(
        const unsigned int* __restrict__ part, const int* __restrict__ bucketCnt,
        unsigned short* __restrict__ srcs16, int* __restrict__ row_ptr,
        int N, int NBK, int E) {
    __shared__ int hist[256], basep[256], wsum[4], sums[4];
    __shared__ unsigned short sbuf[CAPB];
    __shared__ int s_outBase, s_cnt;
    int t = threadIdx.x;          // 0..1023
    int b = blockIdx.x;           // bucket id
    int lane = t & 63, wid = t >> 6;

    // init hist + compute outBase (prefix over bucketCnt[0..b)) with waves 0-3
    if (t < 256) {
        hist[t] = 0;
        int c = (t < NBK && t < b) ? bucketCnt[t] : 0;
        #pragma unroll
        for (int off = 1; off < 64; off <<= 1) c += __shfl_xor(c, off, 64);
        if (lane == 0) sums[wid] = c;
    }
    if (t == 1023) s_cnt = min(bucketCnt[b], CAPB);
    __syncthreads();
    if (t == 0) s_outBase = sums[0] + sums[1] + sums[2] + sums[3];
    __syncthreads();
    int cnt = s_cnt;
    int outBase = s_outBase;
    int s0 = b * CAPB;

    // pass 1: read + histogram; atomic return value IS the within-dst rank
    unsigned int pk[CAPB / 1024];
    int rk[CAPB / 1024];
    #pragma unroll
    for (int u = 0; u < CAPB / 1024; ++u) {
        int i = t + u * 1024;
        if (i < cnt) {
            pk[u] = part[s0 + i];
            rk[u] = atomicAdd(&hist[(pk[u] >> 16) & 255], 1);
        }
    }
    __syncthreads();

    // 256-entry exclusive scan of hist -> basep (waves 0-3)
    if (t < 256) {
        int v = hist[t];
        int x = v;
        #pragma unroll
        for (int off = 1; off < 64; off <<= 1) {
            int y = __shfl_up(x, off, 64);
            if (lane >= off) x += y;
        }
        if (lane == 63) wsum[wid] = x;
        basep[t] = x - v;   // wave-local exclusive; add wave prefix after barrier
    }
    __syncthreads();
    if (t < 256) {
        int wpre = 0;
        #pragma unroll
        for (int w = 0; w < 4; ++w) wpre += (w < wid) ? wsum[w] : 0;
        basep[t] += wpre;
    }
    __syncthreads();

    // scatter into LDS staging at final within-bucket position
    #pragma unroll
    for (int u = 0; u < CAPB / 1024; ++u) {
        int i = t + u * 1024;
        if (i < cnt) {
            int d = (pk[u] >> 16) & 255;
            int pos = basep[d] + rk[u];
            if (pos < CAPB) sbuf[pos] = (unsigned short)(pk[u] & 0xFFFFu);
        }
    }
    __syncthreads();

    // coalesced dump + row_ptr
    for (int i = t; i < cnt; i += 1024)
        srcs16[outBase + i] = sbuf[i];
    if (t < 256) {
        int node = (b << 8) + t;
        if (node < N) row_ptr[node] = outBase + basep[t];
    }
    if (b == 0 && t == 1023) row_ptr[N] = E;
}

// ---------------- per-node softmax attention (fp8 interleaved KV) ----------------
// One wave per dst node. Alpha: lane (head h5 = lane&32, c = lane&31) does
// edge c's 32-dim dot in-lane: 2 x 16B fp8 loads -> direct fp8->f16 cvt
// (v_cvt_pk_f16_fp8, exact: every e4m3 value is f16-representable) -> fdot2
// vs f16 Q, 4 partial chains. Cross-chunk pipeline: srcs prefetched 1 chunk
// ahead; next chunk's K loads issued before the V phase.
// V phase (R14, batched): fixed 8 edge-groups of 4; 16 shfls back-to-back,
// then 8 independent 4B gathers in flight, then 32 fmas.
__global__ __launch_bounds__(256) void k_attn(
        const _Float16* __restrict__ Q, const unsigned char* __restrict__ KV8,
        const int* __restrict__ row_ptr,
        const unsigned short* __restrict__ srcs16, float* __restrict__ out, int N) {
    int lane = threadIdx.x & 63;
    int wave = threadIdx.x >> 6;
    int n = blockIdx.x * 4 + wave;
    if (n >= N) return;
    int h5 = lane & 32;            // head offset (alpha half AND channel head)
    int c  = lane & 31;
    int eg = (lane >> 3) & 3;      // V-phase edge slot [0,4)
    int ch = lane & 7;             // V-phase 4B channel chunk [0,8)

    int start = row_ptr[n];
    int deg   = row_ptr[n + 1] - start;
    if (deg <= 0) return;          // out already holds the skip term

    h8 q8[4];
    {
        const h8* qp = (const h8*)(Q + ((size_t)n << 6) + h5);
        #pragma unroll
        for (int r = 0; r < 4; ++r) q8[r] = qp[r];
    }
    const h2* q2 = (const h2*)q8;  // 16 channel pairs

    const float scale = 0.17677669529663687f;  // 1/sqrt(32)
    float lsum = 0.f;
    f4 acc = (f4){0.f, 0.f, 0.f, 0.f};

    // 32-bit voffset pieces (KV8 stays the SGPR base everywhere)
    unsigned vofs = 64u + (unsigned)h5 + ((unsigned)ch << 2);

    // pipeline prologue: chunk 0's src + K loads
    int sc_cur = (c < deg) ? (int)srcs16[start + c] : 0;
    uint4 ka, kb;
    {
        unsigned ko = ((unsigned)sc_cur << 7) + (unsigned)h5;
        ka = *(const uint4*)(KV8 + ko);
        kb = *(const uint4*)(KV8 + ko + 16);
    }

    for (int i0 = 0; i0 < deg; i0 += 32) {
        int nb = min(32, deg - i0);
        int sc = sc_cur;
        int i1 = i0 + 32;

        // prefetch next chunk's src indices
        int sc_next = 0;
        if (i1 < deg && c < deg - i1) sc_next = (int)srcs16[start + i1 + c];

        // dot for this chunk (consumes ka/kb); 4 partial chains
        float s0 = 0.f, s1 = 0.f, s2 = 0.f, s3 = 0.f;
#ifdef HAVE_PKF16FP8
#define KDOT(kw, idx, ss) { \
        h2 p01 = __builtin_amdgcn_cvt_pk_f16_fp8((short)((kw) & 0xFFFFu)); \
        h2 p23 = __builtin_amdgcn_cvt_pk_f16_fp8((short)((kw) >> 16)); \
        ss = fdot2(p01, q2[2*(idx)],   ss); \
        ss = fdot2(p23, q2[2*(idx)+1], ss); }
#else
#define KDOT(kw, idx, ss) { \
        f2v f01 = __builtin_amdgcn_cvt_pk_f32_fp8((int)(kw), false); \
        f2v f23 = __builtin_amdgcn_cvt_pk_f32_fp8((int)(kw), true);  \
        auto p01 = __builtin_amdgcn_cvt_pkrtz(f01[0], f01[1]); \
        auto p23 = __builtin_amdgcn_cvt_pkrtz(f23[0], f23[1]); \
        ss = fdot2(*(h2*)&p01, q2[2*(idx)],   ss); \
        ss = fdot2(*(h2*)&p23, q2[2*(idx)+1], ss); }
#endif
        KDOT(ka.x, 0, s0) KDOT(ka.y, 1, s1) KDOT(ka.z, 2, s2) KDOT(ka.w, 3, s3)
        KDOT(kb.x, 4, s0) KDOT(kb.y, 5, s1) KDOT(kb.z, 6, s2) KDOT(kb.w, 7, s3)
#undef KDOT
        float s = (s0 + s1) + (s2 + s3);
        float ex = (c < nb) ? __expf(s * scale) : 0.f;
        lsum += ex;

        // issue next chunk's K loads now; they fly during the V phase
        if (i1 < deg) {
            unsigned ko = ((unsigned)sc_next << 7) + (unsigned)h5;
            ka = *(const uint4*)(KV8 + ko);
            kb = *(const uint4*)(KV8 + ko + 16);
        }
        sc_cur = sc_next;

        // ---- batched V phase: fixed 8 groups of 4 edges ----
        float wv[8]; int sj[8];
        #pragma unroll
        for (int u = 0; u < 8; ++u) {
            int j = 4 * u + eg;
            wv[u] = __shfl(ex, h5 + j, 64);  // 0 beyond nb
            sj[u] = __shfl(sc, h5 + j, 64);  // row 0 beyond nb (safe)
        }
        unsigned vw[8];
        #pragma unroll
        for (int u = 0; u < 8; ++u)
            vw[u] = *(const unsigned int*)(KV8 + (((unsigned)sj[u] << 7) + vofs));
        #pragma unroll
        for (int u = 0; u < 8; ++u) {
            f2v v01 = __builtin_amdgcn_cvt_pk_f32_fp8((int)vw[u], false);
            f2v v23 = __builtin_amdgcn_cvt_pk_f32_fp8((int)vw[u], true);
            acc[0] = fmaf(wv[u], v01[0], acc[0]);
            acc[1] = fmaf(wv[u], v01[1], acc[1]);
            acc[2] = fmaf(wv[u], v23[0], acc[2]);
            acc[3] = fmaf(wv[u], v23[1], acc[3]);
        }
    }

    // fold edge slots (lanes ^8 and ^16 share my channel chunk)
    #pragma unroll
    for (int i = 0; i < 4; ++i) {
        acc[i] += __shfl_xor(acc[i], 8, 64);
        acc[i] += __shfl_xor(acc[i], 16, 64);
    }

    // per-head denominator (reduce within my half)
    float ls = lsum;
    ls += __shfl_xor(ls, 16, 64);
    ls += __shfl_xor(ls,  8, 64);
    ls += __shfl_xor(ls,  4, 64);
    ls += __shfl_xor(ls,  2, 64);
    ls += __shfl_xor(ls,  1, 64);
    float rden = 1.0f / fmaxf(ls, 1e-16f);

    if ((lane & 24) == 0) {  // lanes 0-7 (head 0) and 32-39 (head 1)
        float4* o4 = (float4*)out + ((size_t)n << 4) + (h5 >> 2) + ch;
        float4 cur4 = *o4;
        cur4.x += acc[0] * rden;
        cur4.y += acc[1] * rden;
        cur4.z += acc[2] * rden;
        cur4.w += acc[3] * rden;
        *o4 = cur4;
    }
}

// ---------------- launch ----------------
extern "C" void kernel_launch(void* const* d_in, const int* in_sizes, int n_in,
                              void* d_out, int out_size, void* d_ws, size_t ws_size,
                              hipStream_t stream) {
    const float* x  = (const float*)d_in[0];
    const int*   ei = (const int*)d_in[1];
    const float* Wq = (const float*)d_in[2];
    const float* bq = (const float*)d_in[3];
    const float* Wk = (const float*)d_in[4];
    const float* bk = (const float*)d_in[5];
    const float* Wv = (const float*)d_in[6];
    const float* bv = (const float*)d_in[7];
    const float* Ws = (const float*)d_in[8];
    const float* bs = (const float*)d_in[9];
    float* out = (float*)d_out;

    int N = in_sizes[0] / DIN;
    int E = in_sizes[1] / 2;
    int NBK = (N + 255) >> 8;   // 196 coarse buckets

    char* ws = (char*)d_ws;
    size_t off = 0;
    auto carve = [&](size_t bytes) -> void* {
        void* p = ws + off;
        off = (off + bytes + 255) & ~(size_t)255;
        return p;
    };
    int*            bucketCnt = (int*)carve(256 * sizeof(int));
    int*            row_ptr   = (int*)carve((size_t)(N + 1) * sizeof(int));
    unsigned int*   part      = (unsigned int*)carve((size_t)NBK * CAPB * sizeof(unsigned int));
    unsigned short* srcs16    = (unsigned short*)carve((size_t)E * sizeof(unsigned short));
    _Float16*       Wh        = (_Float16*)carve(4 * 8192 * sizeof(_Float16));
    _Float16*       Qh        = (_Float16*)carve((size_t)N * HC * sizeof(_Float16));
    unsigned char*  KV8       = (unsigned char*)carve((size_t)N * 128);
    (void)ws_size; (void)n_in; (void)out_size;

    int qb = (N + TB - 1) / TB;          // GEMM blocks (782 at TB=64)
    int cb = (E + EPB - 1) / EPB;        // partition blocks (391)

    k_prep<<<128, 256, 0, stream>>>(Wq, Wk, Wv, Ws, Wh, bucketCnt);
    k_fused<<<qb + cb, 512, 0, stream>>>(
        (const float4*)x, Wh, bq, bk, bv, bs,
        Qh, KV8, out, N,
        ei, bucketCnt, part, E, cb);
    k_build<<<NBK, 1024, 0, stream>>>(part, bucketCnt, srcs16, row_ptr, N, NBK, E);
    k_attn<<<(N + 3) / 4, 256, 0, stream>>>(Qh, KV8, row_ptr, srcs16, out, N);
}

// Round 9
// 160.426 us; speedup vs baseline: 1.0156x; 1.0156x over previous
//
#include <hip/hip_runtime.h>
#include <hip/hip_bf16.h>

// N = 50000 nodes, E = 1.6M edges, D_IN = 128, H = 2 heads, C = 32 (HC=64).
// 4 dispatches (R20 = R19 + partition/build coalescing + attn 512-blocks):
//   k_prep:  W fp32 -> f16 MFMA-B-frag layout; block 0 zeroes bucketCnt.
//   k_fused: 512-thread blocks. [blocks < cb] partition 8192 edges/block by
//            dst>>8 into padded bucket regions (int4 edge loads, rank-from-
//            histogram, wave-shfl scan; 128B part runs -> full-line writes);
//            [rest] ELU + 4 GEMMs via MFMA f16, TB=64, 8 waves.
//   k_build: ONE 1024-thread block per bucket: uint4 part reads, rank-from-
//            histogram counting sort in regs+LDS, coalesced dump.
//   k_attn:  wave-per-node softmax, fp8 KV gathers, batched V phase (R14);
//            512-thread blocks (8 nodes each).
// History: R10 L2-capacity => fp8 KV; R13 4B V gather; R14 batched V phase;
// R15 partition-first + rank-trick; R16 direct-atomic CSR REGRESSED 2x
// (WRITE_SIZE 40->146MB, write-allocate on random 2B stores) - bucketing
// exists to coalesce the scatter; R17 1-block k_build (165.4); R18 TB=64
// GEMM + int4 loads (162.1); R19 fp8->f16 cvt NEUTRAL (attn latency-bound,
// not VALU-bound - stop shaving dot-phase ops). R20 (this round): EPB 8192
// (part runs 64B->128B), uint4 k_build reads, attn 8 nodes/block.
// NOTE: dur_us includes ~88us of harness 256MiB workspace fills (2/iter,
// top-5 is all fills); controllable kernel budget is ~74us.

#define DIN 128
#define HC  64
#define EPB 8192        // edges per partition block (mean run/bucket = 32 = 128B)
#define CAPB 12288      // padded bucket capacity (mean 8163, sigma ~90)

typedef _Float16 h2 __attribute__((ext_vector_type(2)));
typedef _Float16 h4 __attribute__((ext_vector_type(4)));
typedef _Float16 h8 __attribute__((ext_vector_type(8)));
typedef float    f4 __attribute__((ext_vector_type(4)));
typedef float    f2v __attribute__((ext_vector_type(2)));

#if defined(__has_builtin)
#if __has_builtin(__builtin_amdgcn_fdot2)
#define HAVE_FDOT2 1
#endif
#if __has_builtin(__builtin_amdgcn_cvt_pk_f16_fp8)
#define HAVE_PKF16FP8 1
#endif
#endif

static __device__ __forceinline__ float fdot2(h2 a, h2 b, float c) {
#ifdef HAVE_FDOT2
    return __builtin_amdgcn_fdot2(a, b, c, false);
#else
    return fmaf((float)a.x, (float)b.x, fmaf((float)a.y, (float)b.y, c));
#endif
}

// ---------------- prep: W fp32 -> f16 in MFMA B-fragment layout ----------------
__global__ __launch_bounds__(256) void k_prep(
        const float* __restrict__ Wq, const float* __restrict__ Wk,
        const float* __restrict__ Wv, const float* __restrict__ Ws,
        _Float16* __restrict__ Wh, int* __restrict__ bucketCnt) {
    int t = threadIdx.x;
    if (blockIdx.x == 0) bucketCnt[t] = 0;
    int idx = blockIdx.x * 256 + t;   // 0 .. 32767
    int m    = idx >> 13;
    int rem  = idx & 8191;
    int grp  = rem >> 9;          // ks*4 + nt
    int ks   = grp >> 2;
    int nt   = grp & 3;
    int r3   = rem & 511;
    int lane = r3 >> 3;
    int j    = r3 & 7;
    int k = ks * 32 + (lane >> 4) * 8 + j;
    int n = nt * 16 + (lane & 15);
    const float* W = (m == 0) ? Wq : (m == 1) ? Wk : (m == 2) ? Wv : Ws;
    Wh[idx] = (_Float16)W[k * 64 + n];
}

// ---------------- fused: edge partition (first) + MFMA GEMM (TB=64) ----------
#define TB 64
#define XS 136   // f16 stride per node row (128 + 8 pad)
__global__ __launch_bounds__(512) void k_fused(
        const float4* __restrict__ x4,
        const _Float16* __restrict__ Wh,
        const float* __restrict__ bq, const float* __restrict__ bk,
        const float* __restrict__ bv, const float* __restrict__ bs,
        _Float16* __restrict__ Q, unsigned char* __restrict__ KV8,
        float* __restrict__ OUT, int N,
        const int* __restrict__ ei, int* __restrict__ bucketCnt,
        unsigned int* __restrict__ part, int E, int cb) {
    __shared__ alignas(16) char smem[4096 + EPB * 4];   // 36.9 KB (GEMM uses 17.4)
    int t = threadIdx.x;
    int lane = t & 63, wid = t >> 6;

    if ((int)blockIdx.x < cb) {
        // ---------------- partition role (longest jobs -> dispatched first) ----
        int* hist  = (int*)smem;          // 256: counts (atomic rank source)
        int* lbase = hist + 256;          // 256: exclusive prefix
        int* gbase = lbase + 256;         // 256: global run base
        int* wsum  = gbase + 256;         // 4: wave sums for the scan
        unsigned int* stg = (unsigned int*)(smem + 4096);

        int e0 = (int)blockIdx.x * EPB;
        int cnt = min(EPB, E - e0);
        if (t < 256) hist[t] = 0;
        __syncthreads();

        // pass 1: pack + histogram; atomic return value IS the in-bucket rank.
        // Full blocks: int4 loads (4 edges each, 4 per thread).
        unsigned int pk[EPB / 512];
        unsigned short rk[EPB / 512];
        if (cnt == EPB) {
            const int4* s4 = (const int4*)(ei + e0);
            const int4* d4 = (const int4*)(ei + E + e0);
            #pragma unroll
            for (int u = 0; u < EPB / 2048; ++u) {
                int vi = t + u * 512;
                int4 sv = s4[vi];
                int4 dv = d4[vi];
                unsigned int* p = &pk[u * 4];
                p[0] = ((unsigned)dv.x << 16) | (unsigned)sv.x;
                p[1] = ((unsigned)dv.y << 16) | (unsigned)sv.y;
                p[2] = ((unsigned)dv.z << 16) | (unsigned)sv.z;
                p[3] = ((unsigned)dv.w << 16) | (unsigned)sv.w;
                #pragma unroll
                for (int q = 0; q < 4; ++q)
                    rk[u * 4 + q] = (unsigned short)atomicAdd(&hist[p[q] >> 24], 1);
            }
        } else {
            #pragma unroll
            for (int u = 0; u < EPB / 512; ++u) {
                int i = t + u * 512;
                if (i < cnt) {
                    unsigned int d = (unsigned int)ei[E + e0 + i];
                    unsigned int s = (unsigned int)ei[e0 + i];
                    pk[u] = (d << 16) | s;
                    rk[u] = (unsigned short)atomicAdd(&hist[d >> 8], 1);
                }
            }
        }
        __syncthreads();

        // 256-entry exclusive scan (waves 0-3) + bucket-region reservation
        if (t < 256) {
            int v = hist[t];
            int x = v;
            #pragma unroll
            for (int off = 1; off < 64; off <<= 1) {
                int y = __shfl_up(x, off, 64);
                if (lane >= off) x += y;
            }
            if (lane == 63) wsum[wid] = x;
            lbase[t] = x - v;             // wave-local exclusive part
        }
        __syncthreads();
        if (t < 256) {
            int wpre = 0;
            #pragma unroll
            for (int w = 0; w < 4; ++w) wpre += (w < wid) ? wsum[w] : 0;
            lbase[t] += wpre;
            int v = hist[t];
            if (v > 0) {
                int base = atomicAdd(&bucketCnt[t], v);
                base = min(base, CAPB - v);   // clamp: never cross bucket region
                gbase[t] = t * CAPB + base;
            }
        }
        __syncthreads();

        // scatter straight to LDS staging via rank (no second atomic pass)
        if (cnt == EPB) {
            #pragma unroll
            for (int u = 0; u < EPB / 512; ++u)
                stg[lbase[pk[u] >> 24] + (int)rk[u]] = pk[u];
        } else {
            #pragma unroll
            for (int u = 0; u < EPB / 512; ++u) {
                int i = t + u * 512;
                if (i < cnt) stg[lbase[pk[u] >> 24] + (int)rk[u]] = pk[u];
            }
        }
        __syncthreads();
        // contiguous dump per bucket run (mean 128B runs -> full-line writes)
        for (int i = t; i < cnt; i += 512) {
            unsigned int pkv = stg[i];
            int b = pkv >> 24;
            part[gbase[b] + (i - lbase[b])] = pkv;
        }
        return;
    }

    // ---------------- GEMM role (MFMA f16, 64 nodes/block, 8 waves) ----------
    _Float16* xs = (_Float16*)smem;   // [64][XS]
    int n0 = ((int)blockIdx.x - cb) * TB;

    #pragma unroll
    for (int u = 0; u < 4; ++u) {
        int idx = t + u * 512;        // 0..2047
        int row = idx >> 5;           // 0..63
        int k4  = idx & 31;
        int node = n0 + row;
        float4 v = make_float4(0.f, 0.f, 0.f, 0.f);
        if (node < N) v = x4[(size_t)node * 32 + k4];
        v.x = (v.x > 0.f) ? v.x : (__expf(v.x) - 1.0f);
        v.y = (v.y > 0.f) ? v.y : (__expf(v.y) - 1.0f);
        v.z = (v.z > 0.f) ? v.z : (__expf(v.z) - 1.0f);
        v.w = (v.w > 0.f) ? v.w : (__expf(v.w) - 1.0f);
        h4 hv = { (_Float16)v.x, (_Float16)v.y, (_Float16)v.z, (_Float16)v.w };
        *(h4*)&xs[row * XS + k4 * 4] = hv;
    }
    __syncthreads();

    int m    = wid >> 1;         // which matrix (wave-uniform)
    int half = wid & 1;          // row-half [0,2)
    int lr   = lane & 15;
    int lq   = lane >> 4;
    int r0   = half * 32;        // this wave's row base inside the tile

    const _Float16* Wm = Wh + m * 8192;
    const float* bias = (m == 0) ? bq : (m == 1) ? bk : (m == 2) ? bv : bs;

    f4 acc[2][4];
    #pragma unroll
    for (int mt = 0; mt < 2; ++mt)
        #pragma unroll
        for (int nt = 0; nt < 4; ++nt)
            acc[mt][nt] = (f4){0.f, 0.f, 0.f, 0.f};

    #pragma unroll
    for (int ks = 0; ks < 4; ++ks) {
        h8 a0 = *(const h8*)&xs[(r0 + lr) * XS + ks * 32 + lq * 8];
        h8 a1 = *(const h8*)&xs[(r0 + 16 + lr) * XS + ks * 32 + lq * 8];
        #pragma unroll
        for (int nt = 0; nt < 4; ++nt) {
            h8 b = *(const h8*)&Wm[((ks * 4 + nt) << 9) + lane * 8];
            acc[0][nt] = __builtin_amdgcn_mfma_f32_16x16x32_f16(a0, b, acc[0][nt], 0, 0, 0);
            acc[1][nt] = __builtin_amdgcn_mfma_f32_16x16x32_f16(a1, b, acc[1][nt], 0, 0, 0);
        }
    }

    // epilogue: D lane mapping col = lane&15, row = (lane>>4)*4 + reg
    #pragma unroll
    for (int nt = 0; nt < 4; ++nt) {
        int col = nt * 16 + lr;
        float bb = bias[col];
        #pragma unroll
        for (int mt = 0; mt < 2; ++mt) {
            #pragma unroll
            for (int r = 0; r < 4; ++r) {
                int node = n0 + r0 + mt * 16 + lq * 4 + r;
                if (node < N) {
                    float val = acc[mt][nt][r] + bb;
                    if (m == 3) {
                        OUT[((size_t)node << 6) + col] = val;
                    } else if (m == 0) {
                        Q[((size_t)node << 6) + col] = (_Float16)val;
                    } else {
                        // K -> row bytes [0,64), V -> [64,128)
                        int pk8 = __builtin_amdgcn_cvt_pk_fp8_f32(val, val, 0, false);
                        KV8[((size_t)node << 7) + ((m == 2) ? 64 : 0) + col] =
                            (unsigned char)(pk8 & 0xFF);
                    }
                }
            }
        }
    }
}

// ---------------- build: one 1024-thread block per bucket ----------------
// Counting sort of one bucket (<=CAPB edges): uint4 part reads (12 edges/
// thread in regs), rank-from-histogram, one 256-scan, LDS scatter,
// coalesced dump.
__global__ __launch_bounds__(1024) void k_build(
        const unsigned int* __restrict__ part, const int* __restrict__ bucketCnt,
        unsigned short* __restrict__ srcs16, int* __restrict__ row_ptr,
        int N, int NBK, int E) {
    __shared__ int hist[256], basep[256], wsum[4], sums[4];
    __shared__ unsigned short sbuf[CAPB];
    __shared__ int s_outBase, s_cnt;
    int t = threadIdx.x;          // 0..1023
    int b = blockIdx.x;           // bucket id
    int lane = t & 63, wid = t >> 6;

    // init hist + compute outBase (prefix over bucketCnt[0..b)) with waves 0-3
    if (t < 256) {
        hist[t] = 0;
        int c = (t < NBK && t < b) ? bucketCnt[t] : 0;
        #pragma unroll
        for (int off = 1; off < 64; off <<= 1) c += __shfl_xor(c, off, 64);
        if (lane == 0) sums[wid] = c;
    }
    if (t == 1023) s_cnt = min(bucketCnt[b], CAPB);
    __syncthreads();
    if (t == 0) s_outBase = sums[0] + sums[1] + sums[2] + sums[3];
    __syncthreads();
    int cnt = s_cnt;
    int outBase = s_outBase;
    int s0 = b * CAPB;

    // pass 1: read (uint4 main + scalar tail) + histogram; atomic return
    // value IS the within-dst rank
    unsigned int pk[CAPB / 1024];      // 12 slots
    int rk[CAPB / 1024];
    int cnt4 = cnt >> 2;               // full uint4 groups
    const uint4* p4 = (const uint4*)(part + s0);
    #pragma unroll
    for (int u = 0; u < CAPB / 4096; ++u) {   // 3 iterations
        int i4 = t + u * 1024;
        if (i4 < cnt4) {
            uint4 w = p4[i4];
            unsigned int* p = &pk[u * 4];
            p[0] = w.x; p[1] = w.y; p[2] = w.z; p[3] = w.w;
            #pragma unroll
            for (int q = 0; q < 4; ++q)
                rk[u * 4 + q] = atomicAdd(&hist[(p[q] >> 16) & 255], 1);
        }
    }
    unsigned int pkT = 0; int rkT = -1;
    {
        int j = (cnt4 << 2) + t;       // tail: at most 3 elements
        if (t < 4 && j < cnt) {
            pkT = part[s0 + j];
            rkT = atomicAdd(&hist[(pkT >> 16) & 255], 1);
        }
    }
    __syncthreads();

    // 256-entry exclusive scan of hist -> basep (waves 0-3)
    if (t < 256) {
        int v = hist[t];
        int x = v;
        #pragma unroll
        for (int off = 1; off < 64; off <<= 1) {
            int y = __shfl_up(x, off, 64);
            if (lane >= off) x += y;
        }
        if (lane == 63) wsum[wid] = x;
        basep[t] = x - v;   // wave-local exclusive; add wave prefix after barrier
    }
    __syncthreads();
    if (t < 256) {
        int wpre = 0;
        #pragma unroll
        for (int w = 0; w < 4; ++w) wpre += (w < wid) ? wsum[w] : 0;
        basep[t] += wpre;
    }
    __syncthreads();

    // scatter into LDS staging at final within-bucket position
    #pragma unroll
    for (int u = 0; u < CAPB / 4096; ++u) {
        int i4 = t + u * 1024;
        if (i4 < cnt4) {
            #pragma unroll
            for (int q = 0; q < 4; ++q) {
                unsigned int pkv = pk[u * 4 + q];
                int d = (pkv >> 16) & 255;
                int pos = basep[d] + rk[u * 4 + q];
                if (pos < CAPB) sbuf[pos] = (unsigned short)(pkv & 0xFFFFu);
            }
        }
    }
    if (rkT >= 0) {
        int d = (pkT >> 16) & 255;
        int pos = basep[d] + rkT;
        if (pos < CAPB) sbuf[pos] = (unsigned short)(pkT & 0xFFFFu);
    }
    __syncthreads();

    // coalesced dump + row_ptr
    for (int i = t; i < cnt; i += 1024)
        srcs16[outBase + i] = sbuf[i];
    if (t < 256) {
        int node = (b << 8) + t;
        if (node < N) row_ptr[node] = outBase + basep[t];
    }
    if (b == 0 && t == 1023) row_ptr[N] = E;
}

// ---------------- per-node softmax attention (fp8 interleaved KV) ----------------
// One wave per dst node, 8 nodes per 512-thread block (no LDS/barriers ->
// waves retire individually). Alpha: lane (head h5 = lane&32, c = lane&31)
// does edge c's 32-dim dot in-lane; 4 partial chains. Cross-chunk pipeline:
// srcs prefetched 1 chunk ahead; next chunk's K loads issued before the V
// phase. V phase (R14, batched): fixed 8 edge-groups of 4; 16 shfls, then 8
// independent 4B gathers in flight, then 32 fmas.
__global__ __launch_bounds__(512) void k_attn(
        const _Float16* __restrict__ Q, const unsigned char* __restrict__ KV8,
        const int* __restrict__ row_ptr,
        const unsigned short* __restrict__ srcs16, float* __restrict__ out, int N) {
    int lane = threadIdx.x & 63;
    int wave = threadIdx.x >> 6;
    int n = blockIdx.x * 8 + wave;
    if (n >= N) return;
    int h5 = lane & 32;            // head offset (alpha half AND channel head)
    int c  = lane & 31;
    int eg = (lane >> 3) & 3;      // V-phase edge slot [0,4)
    int ch = lane & 7;             // V-phase 4B channel chunk [0,8)

    int start = row_ptr[n];
    int deg   = row_ptr[n + 1] - start;
    if (deg <= 0) return;          // out already holds the skip term

    h8 q8[4];
    {
        const h8* qp = (const h8*)(Q + ((size_t)n << 6) + h5);
        #pragma unroll
        for (int r = 0; r < 4; ++r) q8[r] = qp[r];
    }
    const h2* q2 = (const h2*)q8;  // 16 channel pairs

    const float scale = 0.17677669529663687f;  // 1/sqrt(32)
    float lsum = 0.f;
    f4 acc = (f4){0.f, 0.f, 0.f, 0.f};

    // 32-bit voffset pieces (KV8 stays the SGPR base everywhere)
    unsigned vofs = 64u + (unsigned)h5 + ((unsigned)ch << 2);

    // pipeline prologue: chunk 0's src + K loads
    int sc_cur = (c < deg) ? (int)srcs16[start + c] : 0;
    uint4 ka, kb;
    {
        unsigned ko = ((unsigned)sc_cur << 7) + (unsigned)h5;
        ka = *(const uint4*)(KV8 + ko);
        kb = *(const uint4*)(KV8 + ko + 16);
    }

    for (int i0 = 0; i0 < deg; i0 += 32) {
        int nb = min(32, deg - i0);
        int sc = sc_cur;
        int i1 = i0 + 32;

        // prefetch next chunk's src indices
        int sc_next = 0;
        if (i1 < deg && c < deg - i1) sc_next = (int)srcs16[start + i1 + c];

        // dot for this chunk (consumes ka/kb); 4 partial chains
        float s0 = 0.f, s1 = 0.f, s2 = 0.f, s3 = 0.f;
#ifdef HAVE_PKF16FP8
#define KDOT(kw, idx, ss) { \
        h2 p01 = __builtin_amdgcn_cvt_pk_f16_fp8((short)((kw) & 0xFFFFu)); \
        h2 p23 = __builtin_amdgcn_cvt_pk_f16_fp8((short)((kw) >> 16)); \
        ss = fdot2(p01, q2[2*(idx)],   ss); \
        ss = fdot2(p23, q2[2*(idx)+1], ss); }
#else
#define KDOT(kw, idx, ss) { \
        f2v f01 = __builtin_amdgcn_cvt_pk_f32_fp8((int)(kw), false); \
        f2v f23 = __builtin_amdgcn_cvt_pk_f32_fp8((int)(kw), true);  \
        auto p01 = __builtin_amdgcn_cvt_pkrtz(f01[0], f01[1]); \
        auto p23 = __builtin_amdgcn_cvt_pkrtz(f23[0], f23[1]); \
        ss = fdot2(*(h2*)&p01, q2[2*(idx)],   ss); \
        ss = fdot2(*(h2*)&p23, q2[2*(idx)+1], ss); }
#endif
        KDOT(ka.x, 0, s0) KDOT(ka.y, 1, s1) KDOT(ka.z, 2, s2) KDOT(ka.w, 3, s3)
        KDOT(kb.x, 4, s0) KDOT(kb.y, 5, s1) KDOT(kb.z, 6, s2) KDOT(kb.w, 7, s3)
#undef KDOT
        float s = (s0 + s1) + (s2 + s3);
        float ex = (c < nb) ? __expf(s * scale) : 0.f;
        lsum += ex;

        // issue next chunk's K loads now; they fly during the V phase
        if (i1 < deg) {
            unsigned ko = ((unsigned)sc_next << 7) + (unsigned)h5;
            ka = *(const uint4*)(KV8 + ko);
            kb = *(const uint4*)(KV8 + ko + 16);
        }
        sc_cur = sc_next;

        // ---- batched V phase: fixed 8 groups of 4 edges ----
        float wv[8]; int sj[8];
        #pragma unroll
        for (int u = 0; u < 8; ++u) {
            int j = 4 * u + eg;
            wv[u] = __shfl(ex, h5 + j, 64);  // 0 beyond nb
            sj[u] = __shfl(sc, h5 + j, 64);  // row 0 beyond nb (safe)
        }
        unsigned vw[8];
        #pragma unroll
        for (int u = 0; u < 8; ++u)
            vw[u] = *(const unsigned int*)(KV8 + (((unsigned)sj[u] << 7) + vofs));
        #pragma unroll
        for (int u = 0; u < 8; ++u) {
            f2v v01 = __builtin_amdgcn_cvt_pk_f32_fp8((int)vw[u], false);
            f2v v23 = __builtin_amdgcn_cvt_pk_f32_fp8((int)vw[u], true);
            acc[0] = fmaf(wv[u], v01[0], acc[0]);
            acc[1] = fmaf(wv[u], v01[1], acc[1]);
            acc[2] = fmaf(wv[u], v23[0], acc[2]);
            acc[3] = fmaf(wv[u], v23[1], acc[3]);
        }
    }

    // fold edge slots (lanes ^8 and ^16 share my channel chunk)
    #pragma unroll
    for (int i = 0; i < 4; ++i) {
        acc[i] += __shfl_xor(acc[i], 8, 64);
        acc[i] += __shfl_xor(acc[i], 16, 64);
    }

    // per-head denominator (reduce within my half)
    float ls = lsum;
    ls += __shfl_xor(ls, 16, 64);
    ls += __shfl_xor(ls,  8, 64);
    ls += __shfl_xor(ls,  4, 64);
    ls += __shfl_xor(ls,  2, 64);
    ls += __shfl_xor(ls,  1, 64);
    float rden = 1.0f / fmaxf(ls, 1e-16f);

    if ((lane & 24) == 0) {  // lanes 0-7 (head 0) and 32-39 (head 1)
        float4* o4 = (float4*)out + ((size_t)n << 4) + (h5 >> 2) + ch;
        float4 cur4 = *o4;
        cur4.x += acc[0] * rden;
        cur4.y += acc[1] * rden;
        cur4.z += acc[2] * rden;
        cur4.w += acc[3] * rden;
        *o4 = cur4;
    }
}

// ---------------- launch ----------------
extern "C" void kernel_launch(void* const* d_in, const int* in_sizes, int n_in,
                              void* d_out, int out_size, void* d_ws, size_t ws_size,
                              hipStream_t stream) {
    const float* x  = (const float*)d_in[0];
    const int*   ei = (const int*)d_in[1];
    const float* Wq = (const float*)d_in[2];
    const float* bq = (const float*)d_in[3];
    const float* Wk = (const float*)d_in[4];
    const float* bk = (const float*)d_in[5];
    const float* Wv = (const float*)d_in[6];
    const float* bv = (const float*)d_in[7];
    const float* Ws = (const float*)d_in[8];
    const float* bs = (const float*)d_in[9];
    float* out = (float*)d_out;

    int N = in_sizes[0] / DIN;
    int E = in_sizes[1] / 2;
    int NBK = (N + 255) >> 8;   // 196 coarse buckets

    char* ws = (char*)d_ws;
    size_t off = 0;
    auto carve = [&](size_t bytes) -> void* {
        void* p = ws + off;
        off = (off + bytes + 255) & ~(size_t)255;
        return p;
    };
    int*            bucketCnt = (int*)carve(256 * sizeof(int));
    int*            row_ptr   = (int*)carve((size_t)(N + 1) * sizeof(int));
    unsigned int*   part      = (unsigned int*)carve((size_t)NBK * CAPB * sizeof(unsigned int));
    unsigned short* srcs16    = (unsigned short*)carve((size_t)E * sizeof(unsigned short));
    _Float16*       Wh        = (_Float16*)carve(4 * 8192 * sizeof(_Float16));
    _Float16*       Qh        = (_Float16*)carve((size_t)N * HC * sizeof(_Float16));
    unsigned char*  KV8       = (unsigned char*)carve((size_t)N * 128);
    (void)ws_size; (void)n_in; (void)out_size;

    int qb = (N + TB - 1) / TB;          // GEMM blocks (782)
    int cb = (E + EPB - 1) / EPB;        // partition blocks (196)

    k_prep<<<128, 256, 0, stream>>>(Wq, Wk, Wv, Ws, Wh, bucketCnt);
    k_fused<<<qb + cb, 512, 0, stream>>>(
        (const float4*)x, Wh, bq, bk, bv, bs,
        Qh, KV8, out, N,
        ei, bucketCnt, part, E, cb);
    k_build<<<NBK, 1024, 0, stream>>>(part, bucketCnt, srcs16, row_ptr, N, NBK, E);
    k_attn<<<(N + 7) / 8, 512, 0, stream>>>(Qh, KV8, row_ptr, srcs16, out, N);
}

// Round 10
// 157.825 us; speedup vs baseline: 1.0323x; 1.0165x over previous
//
#include <hip/hip_runtime.h>
#include <hip/hip_bf16.h>

// N = 50000 nodes, E = 1.6M edges, D_IN = 128, H = 2 heads, C = 32 (HC=64).
// 4 dispatches (R21 = R20 with attn reverted to 256-thread blocks):
//   k_prep:  W fp32 -> f16 MFMA-B-frag layout; block 0 zeroes bucketCnt.
//   k_fused: 512-thread blocks. [blocks < cb] partition 8192 edges/block by
//            dst>>8 into padded bucket regions (int4 edge loads, rank-from-
//            histogram, wave-shfl scan; 128B part runs -> full-line writes);
//            [rest] ELU + 4 GEMMs via MFMA f16, TB=64, 8 waves.
//   k_build: ONE 1024-thread block per bucket: uint4 part reads, rank-from-
//            histogram counting sort in regs+LDS, coalesced dump.
//   k_attn:  wave-per-node softmax, 4 nodes per 256-thread block (R21:
//            512-thread blocks REGRESSED attn 35->45us - max-of-8 degree
//            tail holds workgroup wave slots, occupancy 59->44%).
// History: R10 L2-capacity => fp8 KV; R13 4B V gather; R14 batched V phase;
// R15 partition-first + rank-trick; R16 direct-atomic CSR REGRESSED 2x
// (write-allocate on random 2B stores); R17 1-block k_build (165.4); R18
// TB=64 GEMM (162.1); R19 fp8->f16 cvt NEUTRAL (attn latency-bound); R20
// EPB 8192 + uint4 k_build WON ~12us but attn 512-blocks LOST ~10 (160.4).
// NOTE: dur_us includes ~88us of harness 256MiB workspace fills (2/iter);
// controllable kernel budget is ~72us.

#define DIN 128
#define HC  64
#define EPB 8192        // edges per partition block (mean run/bucket = 32 = 128B)
#define CAPB 12288      // padded bucket capacity (mean 8163, sigma ~90)

typedef _Float16 h2 __attribute__((ext_vector_type(2)));
typedef _Float16 h4 __attribute__((ext_vector_type(4)));
typedef _Float16 h8 __attribute__((ext_vector_type(8)));
typedef float    f4 __attribute__((ext_vector_type(4)));
typedef float    f2v __attribute__((ext_vector_type(2)));

#if defined(__has_builtin)
#if __has_builtin(__builtin_amdgcn_fdot2)
#define HAVE_FDOT2 1
#endif
#if __has_builtin(__builtin_amdgcn_cvt_pk_f16_fp8)
#define HAVE_PKF16FP8 1
#endif
#endif

static __device__ __forceinline__ float fdot2(h2 a, h2 b, float c) {
#ifdef HAVE_FDOT2
    return __builtin_amdgcn_fdot2(a, b, c, false);
#else
    return fmaf((float)a.x, (float)b.x, fmaf((float)a.y, (float)b.y, c));
#endif
}

// ---------------- prep: W fp32 -> f16 in MFMA B-fragment layout ----------------
__global__ __launch_bounds__(256) void k_prep(
        const float* __restrict__ Wq, const float* __restrict__ Wk,
        const float* __restrict__ Wv, const float* __restrict__ Ws,
        _Float16* __restrict__ Wh, int* __restrict__ bucketCnt) {
    int t = threadIdx.x;
    if (blockIdx.x == 0) bucketCnt[t] = 0;
    int idx = blockIdx.x * 256 + t;   // 0 .. 32767
    int m    = idx >> 13;
    int rem  = idx & 8191;
    int grp  = rem >> 9;          // ks*4 + nt
    int ks   = grp >> 2;
    int nt   = grp & 3;
    int r3   = rem & 511;
    int lane = r3 >> 3;
    int j    = r3 & 7;
    int k = ks * 32 + (lane >> 4) * 8 + j;
    int n = nt * 16 + (lane & 15);
    const float* W = (m == 0) ? Wq : (m == 1) ? Wk : (m == 2) ? Wv : Ws;
    Wh[idx] = (_Float16)W[k * 64 + n];
}

// ---------------- fused: edge partition (first) + MFMA GEMM (TB=64) ----------
#define TB 64
#define XS 136   // f16 stride per node row (128 + 8 pad)
__global__ __launch_bounds__(512) void k_fused(
        const float4* __restrict__ x4,
        const _Float16* __restrict__ Wh,
        const float* __restrict__ bq, const float* __restrict__ bk,
        const float* __restrict__ bv, const float* __restrict__ bs,
        _Float16* __restrict__ Q, unsigned char* __restrict__ KV8,
        float* __restrict__ OUT, int N,
        const int* __restrict__ ei, int* __restrict__ bucketCnt,
        unsigned int* __restrict__ part, int E, int cb) {
    __shared__ alignas(16) char smem[4096 + EPB * 4];   // 36.9 KB (GEMM uses 17.4)
    int t = threadIdx.x;
    int lane = t & 63, wid = t >> 6;

    if ((int)blockIdx.x < cb) {
        // ---------------- partition role (longest jobs -> dispatched first) ----
        int* hist  = (int*)smem;          // 256: counts (atomic rank source)
        int* lbase = hist + 256;          // 256: exclusive prefix
        int* gbase = lbase + 256;         // 256: global run base
        int* wsum  = gbase + 256;         // 4: wave sums for the scan
        unsigned int* stg = (unsigned int*)(smem + 4096);

        int e0 = (int)blockIdx.x * EPB;
        int cnt = min(EPB, E - e0);
        if (t < 256) hist[t] = 0;
        __syncthreads();

        // pass 1: pack + histogram; atomic return value IS the in-bucket rank.
        // Full blocks: int4 loads (4 edges each, 4 per thread).
        unsigned int pk[EPB / 512];
        unsigned short rk[EPB / 512];
        if (cnt == EPB) {
            const int4* s4 = (const int4*)(ei + e0);
            const int4* d4 = (const int4*)(ei + E + e0);
            #pragma unroll
            for (int u = 0; u < EPB / 2048; ++u) {
                int vi = t + u * 512;
                int4 sv = s4[vi];
                int4 dv = d4[vi];
                unsigned int* p = &pk[u * 4];
                p[0] = ((unsigned)dv.x << 16) | (unsigned)sv.x;
                p[1] = ((unsigned)dv.y << 16) | (unsigned)sv.y;
                p[2] = ((unsigned)dv.z << 16) | (unsigned)sv.z;
                p[3] = ((unsigned)dv.w << 16) | (unsigned)sv.w;
                #pragma unroll
                for (int q = 0; q < 4; ++q)
                    rk[u * 4 + q] = (unsigned short)atomicAdd(&hist[p[q] >> 24], 1);
            }
        } else {
            #pragma unroll
            for (int u = 0; u < EPB / 512; ++u) {
                int i = t + u * 512;
                if (i < cnt) {
                    unsigned int d = (unsigned int)ei[E + e0 + i];
                    unsigned int s = (unsigned int)ei[e0 + i];
                    pk[u] = (d << 16) | s;
                    rk[u] = (unsigned short)atomicAdd(&hist[d >> 8], 1);
                }
            }
        }
        __syncthreads();

        // 256-entry exclusive scan (waves 0-3) + bucket-region reservation
        if (t < 256) {
            int v = hist[t];
            int x = v;
            #pragma unroll
            for (int off = 1; off < 64; off <<= 1) {
                int y = __shfl_up(x, off, 64);
                if (lane >= off) x += y;
            }
            if (lane == 63) wsum[wid] = x;
            lbase[t] = x - v;             // wave-local exclusive part
        }
        __syncthreads();
        if (t < 256) {
            int wpre = 0;
            #pragma unroll
            for (int w = 0; w < 4; ++w) wpre += (w < wid) ? wsum[w] : 0;
            lbase[t] += wpre;
            int v = hist[t];
            if (v > 0) {
                int base = atomicAdd(&bucketCnt[t], v);
                base = min(base, CAPB - v);   // clamp: never cross bucket region
                gbase[t] = t * CAPB + base;
            }
        }
        __syncthreads();

        // scatter straight to LDS staging via rank (no second atomic pass)
        if (cnt == EPB) {
            #pragma unroll
            for (int u = 0; u < EPB / 512; ++u)
                stg[lbase[pk[u] >> 24] + (int)rk[u]] = pk[u];
        } else {
            #pragma unroll
            for (int u = 0; u < EPB / 512; ++u) {
                int i = t + u * 512;
                if (i < cnt) stg[lbase[pk[u] >> 24] + (int)rk[u]] = pk[u];
            }
        }
        __syncthreads();
        // contiguous dump per bucket run (mean 128B runs -> full-line writes)
        for (int i = t; i < cnt; i += 512) {
            unsigned int pkv = stg[i];
            int b = pkv >> 24;
            part[gbase[b] + (i - lbase[b])] = pkv;
        }
        return;
    }

    // ---------------- GEMM role (MFMA f16, 64 nodes/block, 8 waves) ----------
    _Float16* xs = (_Float16*)smem;   // [64][XS]
    int n0 = ((int)blockIdx.x - cb) * TB;

    #pragma unroll
    for (int u = 0; u < 4; ++u) {
        int idx = t + u * 512;        // 0..2047
        int row = idx >> 5;           // 0..63
        int k4  = idx & 31;
        int node = n0 + row;
        float4 v = make_float4(0.f, 0.f, 0.f, 0.f);
        if (node < N) v = x4[(size_t)node * 32 + k4];
        v.x = (v.x > 0.f) ? v.x : (__expf(v.x) - 1.0f);
        v.y = (v.y > 0.f) ? v.y : (__expf(v.y) - 1.0f);
        v.z = (v.z > 0.f) ? v.z : (__expf(v.z) - 1.0f);
        v.w = (v.w > 0.f) ? v.w : (__expf(v.w) - 1.0f);
        h4 hv = { (_Float16)v.x, (_Float16)v.y, (_Float16)v.z, (_Float16)v.w };
        *(h4*)&xs[row * XS + k4 * 4] = hv;
    }
    __syncthreads();

    int m    = wid >> 1;         // which matrix (wave-uniform)
    int half = wid & 1;          // row-half [0,2)
    int lr   = lane & 15;
    int lq   = lane >> 4;
    int r0   = half * 32;        // this wave's row base inside the tile

    const _Float16* Wm = Wh + m * 8192;
    const float* bias = (m == 0) ? bq : (m == 1) ? bk : (m == 2) ? bv : bs;

    f4 acc[2][4];
    #pragma unroll
    for (int mt = 0; mt < 2; ++mt)
        #pragma unroll
        for (int nt = 0; nt < 4; ++nt)
            acc[mt][nt] = (f4){0.f, 0.f, 0.f, 0.f};

    #pragma unroll
    for (int ks = 0; ks < 4; ++ks) {
        h8 a0 = *(const h8*)&xs[(r0 + lr) * XS + ks * 32 + lq * 8];
        h8 a1 = *(const h8*)&xs[(r0 + 16 + lr) * XS + ks * 32 + lq * 8];
        #pragma unroll
        for (int nt = 0; nt < 4; ++nt) {
            h8 b = *(const h8*)&Wm[((ks * 4 + nt) << 9) + lane * 8];
            acc[0][nt] = __builtin_amdgcn_mfma_f32_16x16x32_f16(a0, b, acc[0][nt], 0, 0, 0);
            acc[1][nt] = __builtin_amdgcn_mfma_f32_16x16x32_f16(a1, b, acc[1][nt], 0, 0, 0);
        }
    }

    // epilogue: D lane mapping col = lane&15, row = (lane>>4)*4 + reg
    #pragma unroll
    for (int nt = 0; nt < 4; ++nt) {
        int col = nt * 16 + lr;
        float bb = bias[col];
        #pragma unroll
        for (int mt = 0; mt < 2; ++mt) {
            #pragma unroll
            for (int r = 0; r < 4; ++r) {
                int node = n0 + r0 + mt * 16 + lq * 4 + r;
                if (node < N) {
                    float val = acc[mt][nt][r] + bb;
                    if (m == 3) {
                        OUT[((size_t)node << 6) + col] = val;
                    } else if (m == 0) {
                        Q[((size_t)node << 6) + col] = (_Float16)val;
                    } else {
                        // K -> row bytes [0,64), V -> [64,128)
                        int pk8 = __builtin_amdgcn_cvt_pk_fp8_f32(val, val, 0, false);
                        KV8[((size_t)node << 7) + ((m == 2) ? 64 : 0) + col] =
                            (unsigned char)(pk8 & 0xFF);
                    }
                }
            }
        }
    }
}

// ---------------- build: one 1024-thread block per bucket ----------------
// Counting sort of one bucket (<=CAPB edges): uint4 part reads (12 edges/
// thread in regs), rank-from-histogram, one 256-scan, LDS scatter,
// coalesced dump.
__global__ __launch_bounds__(1024) void k_build(
        const unsigned int* __restrict__ part, const int* __restrict__ bucketCnt,
        unsigned short* __restrict__ srcs16, int* __restrict__ row_ptr,
        int N, int NBK, int E) {
    __shared__ int hist[256], basep[256], wsum[4], sums[4];
    __shared__ unsigned short sbuf[CAPB];
    __shared__ int s_outBase, s_cnt;
    int t = threadIdx.x;          // 0..1023
    int b = blockIdx.x;           // bucket id
    int lane = t & 63, wid = t >> 6;

    // init hist + compute outBase (prefix over bucketCnt[0..b)) with waves 0-3
    if (t < 256) {
        hist[t] = 0;
        int c = (t < NBK && t < b) ? bucketCnt[t] : 0;
        #pragma unroll
        for (int off = 1; off < 64; off <<= 1) c += __shfl_xor(c, off, 64);
        if (lane == 0) sums[wid] = c;
    }
    if (t == 1023) s_cnt = min(bucketCnt[b], CAPB);
    __syncthreads();
    if (t == 0) s_outBase = sums[0] + sums[1] + sums[2] + sums[3];
    __syncthreads();
    int cnt = s_cnt;
    int outBase = s_outBase;
    int s0 = b * CAPB;

    // pass 1: read (uint4 main + scalar tail) + histogram; atomic return
    // value IS the within-dst rank
    unsigned int pk[CAPB / 1024];      // 12 slots
    int rk[CAPB / 1024];
    int cnt4 = cnt >> 2;               // full uint4 groups
    const uint4* p4 = (const uint4*)(part + s0);
    #pragma unroll
    for (int u = 0; u < CAPB / 4096; ++u) {   // 3 iterations
        int i4 = t + u * 1024;
        if (i4 < cnt4) {
            uint4 w = p4[i4];
            unsigned int* p = &pk[u * 4];
            p[0] = w.x; p[1] = w.y; p[2] = w.z; p[3] = w.w;
            #pragma unroll
            for (int q = 0; q < 4; ++q)
                rk[u * 4 + q] = atomicAdd(&hist[(p[q] >> 16) & 255], 1);
        }
    }
    unsigned int pkT = 0; int rkT = -1;
    {
        int j = (cnt4 << 2) + t;       // tail: at most 3 elements
        if (t < 4 && j < cnt) {
            pkT = part[s0 + j];
            rkT = atomicAdd(&hist[(pkT >> 16) & 255], 1);
        }
    }
    __syncthreads();

    // 256-entry exclusive scan of hist -> basep (waves 0-3)
    if (t < 256) {
        int v = hist[t];
        int x = v;
        #pragma unroll
        for (int off = 1; off < 64; off <<= 1) {
            int y = __shfl_up(x, off, 64);
            if (lane >= off) x += y;
        }
        if (lane == 63) wsum[wid] = x;
        basep[t] = x - v;   // wave-local exclusive; add wave prefix after barrier
    }
    __syncthreads();
    if (t < 256) {
        int wpre = 0;
        #pragma unroll
        for (int w = 0; w < 4; ++w) wpre += (w < wid) ? wsum[w] : 0;
        basep[t] += wpre;
    }
    __syncthreads();

    // scatter into LDS staging at final within-bucket position
    #pragma unroll
    for (int u = 0; u < CAPB / 4096; ++u) {
        int i4 = t + u * 1024;
        if (i4 < cnt4) {
            #pragma unroll
            for (int q = 0; q < 4; ++q) {
                unsigned int pkv = pk[u * 4 + q];
                int d = (pkv >> 16) & 255;
                int pos = basep[d] + rk[u * 4 + q];
                if (pos < CAPB) sbuf[pos] = (unsigned short)(pkv & 0xFFFFu);
            }
        }
    }
    if (rkT >= 0) {
        int d = (pkT >> 16) & 255;
        int pos = basep[d] + rkT;
        if (pos < CAPB) sbuf[pos] = (unsigned short)(pkT & 0xFFFFu);
    }
    __syncthreads();

    // coalesced dump + row_ptr
    for (int i = t; i < cnt; i += 1024)
        srcs16[outBase + i] = sbuf[i];
    if (t < 256) {
        int node = (b << 8) + t;
        if (node < N) row_ptr[node] = outBase + basep[t];
    }
    if (b == 0 && t == 1023) row_ptr[N] = E;
}

// ---------------- per-node softmax attention (fp8 interleaved KV) ----------------
// One wave per dst node, 4 nodes per 256-thread block (R21: 8-node blocks
// regressed - degree-tail holds workgroup wave slots). Alpha: lane (head
// h5 = lane&32, c = lane&31) does edge c's 32-dim dot in-lane; 4 partial
// chains. Cross-chunk pipeline: srcs prefetched 1 chunk ahead; next
// chunk's K loads issued before the V phase. V phase (R14, batched):
// fixed 8 edge-groups of 4; 16 shfls, then 8 independent 4B gathers in
// flight, then 32 fmas.
__global__ __launch_bounds__(256) void k_attn(
        const _Float16* __restrict__ Q, const unsigned char* __restrict__ KV8,
        const int* __restrict__ row_ptr,
        const unsigned short* __restrict__ srcs16, float* __restrict__ out, int N) {
    int lane = threadIdx.x & 63;
    int wave = threadIdx.x >> 6;
    int n = blockIdx.x * 4 + wave;
    if (n >= N) return;
    int h5 = lane & 32;            // head offset (alpha half AND channel head)
    int c  = lane & 31;
    int eg = (lane >> 3) & 3;      // V-phase edge slot [0,4)
    int ch = lane & 7;             // V-phase 4B channel chunk [0,8)

    int start = row_ptr[n];
    int deg   = row_ptr[n + 1] - start;
    if (deg <= 0) return;          // out already holds the skip term

    h8 q8[4];
    {
        const h8* qp = (const h8*)(Q + ((size_t)n << 6) + h5);
        #pragma unroll
        for (int r = 0; r < 4; ++r) q8[r] = qp[r];
    }
    const h2* q2 = (const h2*)q8;  // 16 channel pairs

    const float scale = 0.17677669529663687f;  // 1/sqrt(32)
    float lsum = 0.f;
    f4 acc = (f4){0.f, 0.f, 0.f, 0.f};

    // 32-bit voffset pieces (KV8 stays the SGPR base everywhere)
    unsigned vofs = 64u + (unsigned)h5 + ((unsigned)ch << 2);

    // pipeline prologue: chunk 0's src + K loads
    int sc_cur = (c < deg) ? (int)srcs16[start + c] : 0;
    uint4 ka, kb;
    {
        unsigned ko = ((unsigned)sc_cur << 7) + (unsigned)h5;
        ka = *(const uint4*)(KV8 + ko);
        kb = *(const uint4*)(KV8 + ko + 16);
    }

    for (int i0 = 0; i0 < deg; i0 += 32) {
        int nb = min(32, deg - i0);
        int sc = sc_cur;
        int i1 = i0 + 32;

        // prefetch next chunk's src indices
        int sc_next = 0;
        if (i1 < deg && c < deg - i1) sc_next = (int)srcs16[start + i1 + c];

        // dot for this chunk (consumes ka/kb); 4 partial chains
        float s0 = 0.f, s1 = 0.f, s2 = 0.f, s3 = 0.f;
#ifdef HAVE_PKF16FP8
#define KDOT(kw, idx, ss) { \
        h2 p01 = __builtin_amdgcn_cvt_pk_f16_fp8((short)((kw) & 0xFFFFu)); \
        h2 p23 = __builtin_amdgcn_cvt_pk_f16_fp8((short)((kw) >> 16)); \
        ss = fdot2(p01, q2[2*(idx)],   ss); \
        ss = fdot2(p23, q2[2*(idx)+1], ss); }
#else
#define KDOT(kw, idx, ss) { \
        f2v f01 = __builtin_amdgcn_cvt_pk_f32_fp8((int)(kw), false); \
        f2v f23 = __builtin_amdgcn_cvt_pk_f32_fp8((int)(kw), true);  \
        auto p01 = __builtin_amdgcn_cvt_pkrtz(f01[0], f01[1]); \
        auto p23 = __builtin_amdgcn_cvt_pkrtz(f23[0], f23[1]); \
        ss = fdot2(*(h2*)&p01, q2[2*(idx)],   ss); \
        ss = fdot2(*(h2*)&p23, q2[2*(idx)+1], ss); }
#endif
        KDOT(ka.x, 0, s0) KDOT(ka.y, 1, s1) KDOT(ka.z, 2, s2) KDOT(ka.w, 3, s3)
        KDOT(kb.x, 4, s0) KDOT(kb.y, 5, s1) KDOT(kb.z, 6, s2) KDOT(kb.w, 7, s3)
#undef KDOT
        float s = (s0 + s1) + (s2 + s3);
        float ex = (c < nb) ? __expf(s * scale) : 0.f;
        lsum += ex;

        // issue next chunk's K loads now; they fly during the V phase
        if (i1 < deg) {
            unsigned ko = ((unsigned)sc_next << 7) + (unsigned)h5;
            ka = *(const uint4*)(KV8 + ko);
            kb = *(const uint4*)(KV8 + ko + 16);
        }
        sc_cur = sc_next;

        // ---- batched V phase: fixed 8 groups of 4 edges ----
        float wv[8]; int sj[8];
        #pragma unroll
        for (int u = 0; u < 8; ++u) {
            int j = 4 * u + eg;
            wv[u] = __shfl(ex, h5 + j, 64);  // 0 beyond nb
            sj[u] = __shfl(sc, h5 + j, 64);  // row 0 beyond nb (safe)
        }
        unsigned vw[8];
        #pragma unroll
        for (int u = 0; u < 8; ++u)
            vw[u] = *(const unsigned int*)(KV8 + (((unsigned)sj[u] << 7) + vofs));
        #pragma unroll
        for (int u = 0; u < 8; ++u) {
            f2v v01 = __builtin_amdgcn_cvt_pk_f32_fp8((int)vw[u], false);
            f2v v23 = __builtin_amdgcn_cvt_pk_f32_fp8((int)vw[u], true);
            acc[0] = fmaf(wv[u], v01[0], acc[0]);
            acc[1] = fmaf(wv[u], v01[1], acc[1]);
            acc[2] = fmaf(wv[u], v23[0], acc[2]);
            acc[3] = fmaf(wv[u], v23[1], acc[3]);
        }
    }

    // fold edge slots (lanes ^8 and ^16 share my channel chunk)
    #pragma unroll
    for (int i = 0; i < 4; ++i) {
        acc[i] += __shfl_xor(acc[i], 8, 64);
        acc[i] += __shfl_xor(acc[i], 16, 64);
    }

    // per-head denominator (reduce within my half)
    float ls = lsum;
    ls += __shfl_xor(ls, 16, 64);
    ls += __shfl_xor(ls,  8, 64);
    ls += __shfl_xor(ls,  4, 64);
    ls += __shfl_xor(ls,  2, 64);
    ls += __shfl_xor(ls,  1, 64);
    float rden = 1.0f / fmaxf(ls, 1e-16f);

    if ((lane & 24) == 0) {  // lanes 0-7 (head 0) and 32-39 (head 1)
        float4* o4 = (float4*)out + ((size_t)n << 4) + (h5 >> 2) + ch;
        float4 cur4 = *o4;
        cur4.x += acc[0] * rden;
        cur4.y += acc[1] * rden;
        cur4.z += acc[2] * rden;
        cur4.w += acc[3] * rden;
        *o4 = cur4;
    }
}

// ---------------- launch ----------------
extern "C" void kernel_launch(void* const* d_in, const int* in_sizes, int n_in,
                              void* d_out, int out_size, void* d_ws, size_t ws_size,
                              hipStream_t stream) {
    const float* x  = (const float*)d_in[0];
    const int*   ei = (const int*)d_in[1];
    const float* Wq = (const float*)d_in[2];
    const float* bq = (const float*)d_in[3];
    const float* Wk = (const float*)d_in[4];
    const float* bk = (const float*)d_in[5];
    const float* Wv = (const float*)d_in[6];
    const float* bv = (const float*)d_in[7];
    const float* Ws = (const float*)d_in[8];
    const float* bs = (const float*)d_in[9];
    float* out = (float*)d_out;

    int N = in_sizes[0] / DIN;
    int E = in_sizes[1] / 2;
    int NBK = (N + 255) >> 8;   // 196 coarse buckets

    char* ws = (char*)d_ws;
    size_t off = 0;
    auto carve = [&](size_t bytes) -> void* {
        void* p = ws + off;
        off = (off + bytes + 255) & ~(size_t)255;
        return p;
    };
    int*            bucketCnt = (int*)carve(256 * sizeof(int));
    int*            row_ptr   = (int*)carve((size_t)(N + 1) * sizeof(int));
    unsigned int*   part      = (unsigned int*)carve((size_t)NBK * CAPB * sizeof(unsigned int));
    unsigned short* srcs16    = (unsigned short*)carve((size_t)E * sizeof(unsigned short));
    _Float16*       Wh        = (_Float16*)carve(4 * 8192 * sizeof(_Float16));
    _Float16*       Qh        = (_Float16*)carve((size_t)N * HC * sizeof(_Float16));
    unsigned char*  KV8       = (unsigned char*)carve((size_t)N * 128);
    (void)ws_size; (void)n_in; (void)out_size;

    int qb = (N + TB - 1) / TB;          // GEMM blocks (782)
    int cb = (E + EPB - 1) / EPB;        // partition blocks (196)

    k_prep<<<128, 256, 0, stream>>>(Wq, Wk, Wv, Ws, Wh, bucketCnt);
    k_fused<<<qb + cb, 512, 0, stream>>>(
        (const float4*)x, Wh, bq, bk, bv, bs,
        Qh, KV8, out, N,
        ei, bucketCnt, part, E, cb);
    k_build<<<NBK, 1024, 0, stream>>>(part, bucketCnt, srcs16, row_ptr, N, NBK, E);
    k_attn<<<(N + 3) / 4, 256, 0, stream>>>(Qh, KV8, row_ptr, srcs16, out, N);
}

// Round 11
// 157.255 us; speedup vs baseline: 1.0360x; 1.0036x over previous
//
#include <hip/hip_runtime.h>
#include <hip/hip_bf16.h>

// N = 50000 nodes, E = 1.6M edges, D_IN = 128, H = 2 heads, C = 32 (HC=64).
// 4 dispatches (R22 = R21 + per-head 64B KV grouping + 128-thr attn blocks):
//   k_prep:  W fp32 -> f16 MFMA-B-frag layout; block 0 zeroes bucketCnt.
//   k_fused: 512-thread blocks. [blocks < cb] partition 8192 edges/block by
//            dst>>8 into padded bucket regions (int4 edge loads, rank-from-
//            histogram, wave-shfl scan; 128B part runs); [rest] ELU + 4
//            GEMMs via MFMA f16, TB=64, 8 waves. KV8 row layout (R22):
//            K_h0[0,32) V_h0[32,64) K_h1[64,96) V_h1[96,128) -- each head's
//            K and V share one 64B L1 line, so the attn V-phase gather hits
//            L1 on rows the dot phase just fetched.
//   k_build: ONE 1024-thread block per bucket: uint4 part reads, rank-from-
//            histogram counting sort in regs+LDS, coalesced dump.
//   k_attn:  wave-per-node softmax, 2 nodes per 128-thread block (max-of-2
//            degree tail vs max-of-4; 16 blk x 2 waves still hits the
//            32-wave/CU cap).
// History: R10 L2-capacity => fp8 KV; R13 4B V gather; R14 batched V phase;
// R15 partition-first + rank-trick; R16 direct-atomic CSR REGRESSED 2x
// (write-allocate on random 2B stores); R17 1-block k_build; R18 TB=64
// GEMM; R19 fp8->f16 cvt NEUTRAL (attn latency-bound); R20 EPB 8192 +
// uint4 k_build (+12) but attn 512-blocks (-10); R21 attn back to 256-thr
// blocks (157.8). NOTE: dur_us includes ~88us of harness 256MiB fills;
// controllable kernel budget is ~70us.

#define DIN 128
#define HC  64
#define EPB 8192        // edges per partition block (mean run/bucket = 32 = 128B)
#define CAPB 12288      // padded bucket capacity (mean 8163, sigma ~90)

typedef _Float16 h2 __attribute__((ext_vector_type(2)));
typedef _Float16 h4 __attribute__((ext_vector_type(4)));
typedef _Float16 h8 __attribute__((ext_vector_type(8)));
typedef float    f4 __attribute__((ext_vector_type(4)));
typedef float    f2v __attribute__((ext_vector_type(2)));

#if defined(__has_builtin)
#if __has_builtin(__builtin_amdgcn_fdot2)
#define HAVE_FDOT2 1
#endif
#if __has_builtin(__builtin_amdgcn_cvt_pk_f16_fp8)
#define HAVE_PKF16FP8 1
#endif
#endif

static __device__ __forceinline__ float fdot2(h2 a, h2 b, float c) {
#ifdef HAVE_FDOT2
    return __builtin_amdgcn_fdot2(a, b, c, false);
#else
    return fmaf((float)a.x, (float)b.x, fmaf((float)a.y, (float)b.y, c));
#endif
}

// ---------------- prep: W fp32 -> f16 in MFMA B-fragment layout ----------------
__global__ __launch_bounds__(256) void k_prep(
        const float* __restrict__ Wq, const float* __restrict__ Wk,
        const float* __restrict__ Wv, const float* __restrict__ Ws,
        _Float16* __restrict__ Wh, int* __restrict__ bucketCnt) {
    int t = threadIdx.x;
    if (blockIdx.x == 0) bucketCnt[t] = 0;
    int idx = blockIdx.x * 256 + t;   // 0 .. 32767
    int m    = idx >> 13;
    int rem  = idx & 8191;
    int grp  = rem >> 9;          // ks*4 + nt
    int ks   = grp >> 2;
    int nt   = grp & 3;
    int r3   = rem & 511;
    int lane = r3 >> 3;
    int j    = r3 & 7;
    int k = ks * 32 + (lane >> 4) * 8 + j;
    int n = nt * 16 + (lane & 15);
    const float* W = (m == 0) ? Wq : (m == 1) ? Wk : (m == 2) ? Wv : Ws;
    Wh[idx] = (_Float16)W[k * 64 + n];
}

// ---------------- fused: edge partition (first) + MFMA GEMM (TB=64) ----------
#define TB 64
#define XS 136   // f16 stride per node row (128 + 8 pad)
__global__ __launch_bounds__(512) void k_fused(
        const float4* __restrict__ x4,
        const _Float16* __restrict__ Wh,
        const float* __restrict__ bq, const float* __restrict__ bk,
        const float* __restrict__ bv, const float* __restrict__ bs,
        _Float16* __restrict__ Q, unsigned char* __restrict__ KV8,
        float* __restrict__ OUT, int N,
        const int* __restrict__ ei, int* __restrict__ bucketCnt,
        unsigned int* __restrict__ part, int E, int cb) {
    __shared__ alignas(16) char smem[4096 + EPB * 4];   // 36.9 KB (GEMM uses 17.4)
    int t = threadIdx.x;
    int lane = t & 63, wid = t >> 6;

    if ((int)blockIdx.x < cb) {
        // ---------------- partition role (longest jobs -> dispatched first) ----
        int* hist  = (int*)smem;          // 256: counts (atomic rank source)
        int* lbase = hist + 256;          // 256: exclusive prefix
        int* gbase = lbase + 256;         // 256: global run base
        int* wsum  = gbase + 256;         // 4: wave sums for the scan
        unsigned int* stg = (unsigned int*)(smem + 4096);

        int e0 = (int)blockIdx.x * EPB;
        int cnt = min(EPB, E - e0);
        if (t < 256) hist[t] = 0;
        __syncthreads();

        // pass 1: pack + histogram; atomic return value IS the in-bucket rank.
        // Full blocks: int4 loads (4 edges each, 4 per thread).
        unsigned int pk[EPB / 512];
        unsigned short rk[EPB / 512];
        if (cnt == EPB) {
            const int4* s4 = (const int4*)(ei + e0);
            const int4* d4 = (const int4*)(ei + E + e0);
            #pragma unroll
            for (int u = 0; u < EPB / 2048; ++u) {
                int vi = t + u * 512;
                int4 sv = s4[vi];
                int4 dv = d4[vi];
                unsigned int* p = &pk[u * 4];
                p[0] = ((unsigned)dv.x << 16) | (unsigned)sv.x;
                p[1] = ((unsigned)dv.y << 16) | (unsigned)sv.y;
                p[2] = ((unsigned)dv.z << 16) | (unsigned)sv.z;
                p[3] = ((unsigned)dv.w << 16) | (unsigned)sv.w;
                #pragma unroll
                for (int q = 0; q < 4; ++q)
                    rk[u * 4 + q] = (unsigned short)atomicAdd(&hist[p[q] >> 24], 1);
            }
        } else {
            #pragma unroll
            for (int u = 0; u < EPB / 512; ++u) {
                int i = t + u * 512;
                if (i < cnt) {
                    unsigned int d = (unsigned int)ei[E + e0 + i];
                    unsigned int s = (unsigned int)ei[e0 + i];
                    pk[u] = (d << 16) | s;
                    rk[u] = (unsigned short)atomicAdd(&hist[d >> 8], 1);
                }
            }
        }
        __syncthreads();

        // 256-entry exclusive scan (waves 0-3) + bucket-region reservation
        if (t < 256) {
            int v = hist[t];
            int x = v;
            #pragma unroll
            for (int off = 1; off < 64; off <<= 1) {
                int y = __shfl_up(x, off, 64);
                if (lane >= off) x += y;
            }
            if (lane == 63) wsum[wid] = x;
            lbase[t] = x - v;             // wave-local exclusive part
        }
        __syncthreads();
        if (t < 256) {
            int wpre = 0;
            #pragma unroll
            for (int w = 0; w < 4; ++w) wpre += (w < wid) ? wsum[w] : 0;
            lbase[t] += wpre;
            int v = hist[t];
            if (v > 0) {
                int base = atomicAdd(&bucketCnt[t], v);
                base = min(base, CAPB - v);   // clamp: never cross bucket region
                gbase[t] = t * CAPB + base;
            }
        }
        __syncthreads();

        // scatter straight to LDS staging via rank (no second atomic pass)
        if (cnt == EPB) {
            #pragma unroll
            for (int u = 0; u < EPB / 512; ++u)
                stg[lbase[pk[u] >> 24] + (int)rk[u]] = pk[u];
        } else {
            #pragma unroll
            for (int u = 0; u < EPB / 512; ++u) {
                int i = t + u * 512;
                if (i < cnt) stg[lbase[pk[u] >> 24] + (int)rk[u]] = pk[u];
            }
        }
        __syncthreads();
        // contiguous dump per bucket run (mean 128B runs -> full-line writes)
        for (int i = t; i < cnt; i += 512) {
            unsigned int pkv = stg[i];
            int b = pkv >> 24;
            part[gbase[b] + (i - lbase[b])] = pkv;
        }
        return;
    }

    // ---------------- GEMM role (MFMA f16, 64 nodes/block, 8 waves) ----------
    _Float16* xs = (_Float16*)smem;   // [64][XS]
    int n0 = ((int)blockIdx.x - cb) * TB;

    #pragma unroll
    for (int u = 0; u < 4; ++u) {
        int idx = t + u * 512;        // 0..2047
        int row = idx >> 5;           // 0..63
        int k4  = idx & 31;
        int node = n0 + row;
        float4 v = make_float4(0.f, 0.f, 0.f, 0.f);
        if (node < N) v = x4[(size_t)node * 32 + k4];
        v.x = (v.x > 0.f) ? v.x : (__expf(v.x) - 1.0f);
        v.y = (v.y > 0.f) ? v.y : (__expf(v.y) - 1.0f);
        v.z = (v.z > 0.f) ? v.z : (__expf(v.z) - 1.0f);
        v.w = (v.w > 0.f) ? v.w : (__expf(v.w) - 1.0f);
        h4 hv = { (_Float16)v.x, (_Float16)v.y, (_Float16)v.z, (_Float16)v.w };
        *(h4*)&xs[row * XS + k4 * 4] = hv;
    }
    __syncthreads();

    int m    = wid >> 1;         // which matrix (wave-uniform)
    int half = wid & 1;          // row-half [0,2)
    int lr   = lane & 15;
    int lq   = lane >> 4;
    int r0   = half * 32;        // this wave's row base inside the tile

    const _Float16* Wm = Wh + m * 8192;
    const float* bias = (m == 0) ? bq : (m == 1) ? bk : (m == 2) ? bv : bs;

    f4 acc[2][4];
    #pragma unroll
    for (int mt = 0; mt < 2; ++mt)
        #pragma unroll
        for (int nt = 0; nt < 4; ++nt)
            acc[mt][nt] = (f4){0.f, 0.f, 0.f, 0.f};

    #pragma unroll
    for (int ks = 0; ks < 4; ++ks) {
        h8 a0 = *(const h8*)&xs[(r0 + lr) * XS + ks * 32 + lq * 8];
        h8 a1 = *(const h8*)&xs[(r0 + 16 + lr) * XS + ks * 32 + lq * 8];
        #pragma unroll
        for (int nt = 0; nt < 4; ++nt) {
            h8 b = *(const h8*)&Wm[((ks * 4 + nt) << 9) + lane * 8];
            acc[0][nt] = __builtin_amdgcn_mfma_f32_16x16x32_f16(a0, b, acc[0][nt], 0, 0, 0);
            acc[1][nt] = __builtin_amdgcn_mfma_f32_16x16x32_f16(a1, b, acc[1][nt], 0, 0, 0);
        }
    }

    // epilogue: D lane mapping col = lane&15, row = (lane>>4)*4 + reg
    // KV8 row layout (R22): per-head 64B groups -- K_h[64h,64h+32),
    // V_h[64h+32,64h+64): dot-phase K line == V-phase gather line (L1).
    #pragma unroll
    for (int nt = 0; nt < 4; ++nt) {
        int col = nt * 16 + lr;
        float bb = bias[col];
        int head = col >> 5, chh = col & 31;
        int kvoff = (head << 6) + chh;           // K slot; +32 for V
        #pragma unroll
        for (int mt = 0; mt < 2; ++mt) {
            #pragma unroll
            for (int r = 0; r < 4; ++r) {
                int node = n0 + r0 + mt * 16 + lq * 4 + r;
                if (node < N) {
                    float val = acc[mt][nt][r] + bb;
                    if (m == 3) {
                        OUT[((size_t)node << 6) + col] = val;
                    } else if (m == 0) {
                        Q[((size_t)node << 6) + col] = (_Float16)val;
                    } else {
                        int pk8 = __builtin_amdgcn_cvt_pk_fp8_f32(val, val, 0, false);
                        KV8[((size_t)node << 7) + kvoff + ((m == 2) ? 32 : 0)] =
                            (unsigned char)(pk8 & 0xFF);
                    }
                }
            }
        }
    }
}

// ---------------- build: one 1024-thread block per bucket ----------------
// Counting sort of one bucket (<=CAPB edges): uint4 part reads (12 edges/
// thread in regs), rank-from-histogram, one 256-scan, LDS scatter,
// coalesced dump.
__global__ __launch_bounds__(1024) void k_build(
        const unsigned int* __restrict__ part, const int* __restrict__ bucketCnt,
        unsigned short* __restrict__ srcs16, int* __restrict__ row_ptr,
        int N, int NBK, int E) {
    __shared__ int hist[256], basep[256], wsum[4], sums[4];
    __shared__ unsigned short sbuf[CAPB];
    __shared__ int s_outBase, s_cnt;
    int t = threadIdx.x;          // 0..1023
    int b = blockIdx.x;           // bucket id
    int lane = t & 63, wid = t >> 6;

    // init hist + compute outBase (prefix over bucketCnt[0..b)) with waves 0-3
    if (t < 256) {
        hist[t] = 0;
        int c = (t < NBK && t < b) ? bucketCnt[t] : 0;
        #pragma unroll
        for (int off = 1; off < 64; off <<= 1) c += __shfl_xor(c, off, 64);
        if (lane == 0) sums[wid] = c;
    }
    if (t == 1023) s_cnt = min(bucketCnt[b], CAPB);
    __syncthreads();
    if (t == 0) s_outBase = sums[0] + sums[1] + sums[2] + sums[3];
    __syncthreads();
    int cnt = s_cnt;
    int outBase = s_outBase;
    int s0 = b * CAPB;

    // pass 1: read (uint4 main + scalar tail) + histogram; atomic return
    // value IS the within-dst rank
    unsigned int pk[CAPB / 1024];      // 12 slots
    int rk[CAPB / 1024];
    int cnt4 = cnt >> 2;               // full uint4 groups
    const uint4* p4 = (const uint4*)(part + s0);
    #pragma unroll
    for (int u = 0; u < CAPB / 4096; ++u) {   // 3 iterations
        int i4 = t + u * 1024;
        if (i4 < cnt4) {
            uint4 w = p4[i4];
            unsigned int* p = &pk[u * 4];
            p[0] = w.x; p[1] = w.y; p[2] = w.z; p[3] = w.w;
            #pragma unroll
            for (int q = 0; q < 4; ++q)
                rk[u * 4 + q] = atomicAdd(&hist[(p[q] >> 16) & 255], 1);
        }
    }
    unsigned int pkT = 0; int rkT = -1;
    {
        int j = (cnt4 << 2) + t;       // tail: at most 3 elements
        if (t < 4 && j < cnt) {
            pkT = part[s0 + j];
            rkT = atomicAdd(&hist[(pkT >> 16) & 255], 1);
        }
    }
    __syncthreads();

    // 256-entry exclusive scan of hist -> basep (waves 0-3)
    if (t < 256) {
        int v = hist[t];
        int x = v;
        #pragma unroll
        for (int off = 1; off < 64; off <<= 1) {
            int y = __shfl_up(x, off, 64);
            if (lane >= off) x += y;
        }
        if (lane == 63) wsum[wid] = x;
        basep[t] = x - v;   // wave-local exclusive; add wave prefix after barrier
    }
    __syncthreads();
    if (t < 256) {
        int wpre = 0;
        #pragma unroll
        for (int w = 0; w < 4; ++w) wpre += (w < wid) ? wsum[w] : 0;
        basep[t] += wpre;
    }
    __syncthreads();

    // scatter into LDS staging at final within-bucket position
    #pragma unroll
    for (int u = 0; u < CAPB / 4096; ++u) {
        int i4 = t + u * 1024;
        if (i4 < cnt4) {
            #pragma unroll
            for (int q = 0; q < 4; ++q) {
                unsigned int pkv = pk[u * 4 + q];
                int d = (pkv >> 16) & 255;
                int pos = basep[d] + rk[u * 4 + q];
                if (pos < CAPB) sbuf[pos] = (unsigned short)(pkv & 0xFFFFu);
            }
        }
    }
    if (rkT >= 0) {
        int d = (pkT >> 16) & 255;
        int pos = basep[d] + rkT;
        if (pos < CAPB) sbuf[pos] = (unsigned short)(pkT & 0xFFFFu);
    }
    __syncthreads();

    // coalesced dump + row_ptr
    for (int i = t; i < cnt; i += 1024)
        srcs16[outBase + i] = sbuf[i];
    if (t < 256) {
        int node = (b << 8) + t;
        if (node < N) row_ptr[node] = outBase + basep[t];
    }
    if (b == 0 && t == 1023) row_ptr[N] = E;
}

// ---------------- per-node softmax attention (fp8 per-head 64B KV) ----------------
// One wave per dst node, 2 nodes per 128-thread block (max-of-2 degree
// tail; 16 blk x 2 waves reaches the 32-wave/CU cap). Alpha: lane (head
// h5 = lane&32, c = lane&31) does edge c's 32-dim dot in-lane; 4 partial
// chains. KV row layout: K_h[64h,64h+32) V_h[64h+32,64h+64) -- the V-phase
// 4B gather hits the SAME 64B L1 line the dot phase fetched. Cross-chunk
// pipeline: srcs prefetched 1 chunk ahead; next chunk's K loads issued
// before the V phase. V phase (R14, batched): fixed 8 edge-groups of 4;
// 16 shfls, then 8 independent 4B gathers in flight, then 32 fmas.
__global__ __launch_bounds__(128) void k_attn(
        const _Float16* __restrict__ Q, const unsigned char* __restrict__ KV8,
        const int* __restrict__ row_ptr,
        const unsigned short* __restrict__ srcs16, float* __restrict__ out, int N) {
    int lane = threadIdx.x & 63;
    int wave = threadIdx.x >> 6;
    int n = blockIdx.x * 2 + wave;
    if (n >= N) return;
    int h5 = lane & 32;            // head selector (alpha half AND channel head)
    int c  = lane & 31;
    int eg = (lane >> 3) & 3;      // V-phase edge slot [0,4)
    int ch = lane & 7;             // V-phase 4B channel chunk [0,8)

    int start = row_ptr[n];
    int deg   = row_ptr[n + 1] - start;
    if (deg <= 0) return;          // out already holds the skip term

    h8 q8[4];
    {
        const h8* qp = (const h8*)(Q + ((size_t)n << 6) + h5);
        #pragma unroll
        for (int r = 0; r < 4; ++r) q8[r] = qp[r];
    }
    const h2* q2 = (const h2*)q8;  // 16 channel pairs

    const float scale = 0.17677669529663687f;  // 1/sqrt(32)
    float lsum = 0.f;
    f4 acc = (f4){0.f, 0.f, 0.f, 0.f};

    // per-head 64B group base: head h at byte 64h; V at +32
    unsigned kbase = (unsigned)(h5 << 1);            // 0 or 64
    unsigned vofs  = kbase + 32u + ((unsigned)ch << 2);

    // pipeline prologue: chunk 0's src + K loads
    int sc_cur = (c < deg) ? (int)srcs16[start + c] : 0;
    uint4 ka, kb;
    {
        unsigned ko = ((unsigned)sc_cur << 7) + kbase;
        ka = *(const uint4*)(KV8 + ko);
        kb = *(const uint4*)(KV8 + ko + 16);
    }

    for (int i0 = 0; i0 < deg; i0 += 32) {
        int nb = min(32, deg - i0);
        int sc = sc_cur;
        int i1 = i0 + 32;

        // prefetch next chunk's src indices
        int sc_next = 0;
        if (i1 < deg && c < deg - i1) sc_next = (int)srcs16[start + i1 + c];

        // dot for this chunk (consumes ka/kb); 4 partial chains
        float s0 = 0.f, s1 = 0.f, s2 = 0.f, s3 = 0.f;
#ifdef HAVE_PKF16FP8
#define KDOT(kw, idx, ss) { \
        h2 p01 = __builtin_amdgcn_cvt_pk_f16_fp8((short)((kw) & 0xFFFFu)); \
        h2 p23 = __builtin_amdgcn_cvt_pk_f16_fp8((short)((kw) >> 16)); \
        ss = fdot2(p01, q2[2*(idx)],   ss); \
        ss = fdot2(p23, q2[2*(idx)+1], ss); }
#else
#define KDOT(kw, idx, ss) { \
        f2v f01 = __builtin_amdgcn_cvt_pk_f32_fp8((int)(kw), false); \
        f2v f23 = __builtin_amdgcn_cvt_pk_f32_fp8((int)(kw), true);  \
        auto p01 = __builtin_amdgcn_cvt_pkrtz(f01[0], f01[1]); \
        auto p23 = __builtin_amdgcn_cvt_pkrtz(f23[0], f23[1]); \
        ss = fdot2(*(h2*)&p01, q2[2*(idx)],   ss); \
        ss = fdot2(*(h2*)&p23, q2[2*(idx)+1], ss); }
#endif
        KDOT(ka.x, 0, s0) KDOT(ka.y, 1, s1) KDOT(ka.z, 2, s2) KDOT(ka.w, 3, s3)
        KDOT(kb.x, 4, s0) KDOT(kb.y, 5, s1) KDOT(kb.z, 6, s2) KDOT(kb.w, 7, s3)
#undef KDOT
        float s = (s0 + s1) + (s2 + s3);
        float ex = (c < nb) ? __expf(s * scale) : 0.f;
        lsum += ex;

        // issue next chunk's K loads now; they fly during the V phase
        if (i1 < deg) {
            unsigned ko = ((unsigned)sc_next << 7) + kbase;
            ka = *(const uint4*)(KV8 + ko);
            kb = *(const uint4*)(KV8 + ko + 16);
        }
        sc_cur = sc_next;

        // ---- batched V phase: fixed 8 groups of 4 edges ----
        float wv[8]; int sj[8];
        #pragma unroll
        for (int u = 0; u < 8; ++u) {
            int j = 4 * u + eg;
            wv[u] = __shfl(ex, h5 + j, 64);  // 0 beyond nb
            sj[u] = __shfl(sc, h5 + j, 64);  // row 0 beyond nb (safe)
        }
        unsigned vw[8];
        #pragma unroll
        for (int u = 0; u < 8; ++u)
            vw[u] = *(const unsigned int*)(KV8 + (((unsigned)sj[u] << 7) + vofs));
        #pragma unroll
        for (int u = 0; u < 8; ++u) {
            f2v v01 = __builtin_amdgcn_cvt_pk_f32_fp8((int)vw[u], false);
            f2v v23 = __builtin_amdgcn_cvt_pk_f32_fp8((int)vw[u], true);
            acc[0] = fmaf(wv[u], v01[0], acc[0]);
            acc[1] = fmaf(wv[u], v01[1], acc[1]);
            acc[2] = fmaf(wv[u], v23[0], acc[2]);
            acc[3] = fmaf(wv[u], v23[1], acc[3]);
        }
    }

    // fold edge slots (lanes ^8 and ^16 share my channel chunk)
    #pragma unroll
    for (int i = 0; i < 4; ++i) {
        acc[i] += __shfl_xor(acc[i], 8, 64);
        acc[i] += __shfl_xor(acc[i], 16, 64);
    }

    // per-head denominator (reduce within my half)
    float ls = lsum;
    ls += __shfl_xor(ls, 16, 64);
    ls += __shfl_xor(ls,  8, 64);
    ls += __shfl_xor(ls,  4, 64);
    ls += __shfl_xor(ls,  2, 64);
    ls += __shfl_xor(ls,  1, 64);
    float rden = 1.0f / fmaxf(ls, 1e-16f);

    if ((lane & 24) == 0) {  // lanes 0-7 (head 0) and 32-39 (head 1)
        float4* o4 = (float4*)out + ((size_t)n << 4) + (h5 >> 2) + ch;
        float4 cur4 = *o4;
        cur4.x += acc[0] * rden;
        cur4.y += acc[1] * rden;
        cur4.z += acc[2] * rden;
        cur4.w += acc[3] * rden;
        *o4 = cur4;
    }
}

// ---------------- launch ----------------
extern "C" void kernel_launch(void* const* d_in, const int* in_sizes, int n_in,
                              void* d_out, int out_size, void* d_ws, size_t ws_size,
                              hipStream_t stream) {
    const float* x  = (const float*)d_in[0];
    const int*   ei = (const int*)d_in[1];
    const float* Wq = (const float*)d_in[2];
    const float* bq = (const float*)d_in[3];
    const float* Wk = (const float*)d_in[4];
    const float* bk = (const float*)d_in[5];
    const float* Wv = (const float*)d_in[6];
    const float* bv = (const float*)d_in[7];
    const float* Ws = (const float*)d_in[8];
    const float* bs = (const float*)d_in[9];
    float* out = (float*)d_out;

    int N = in_sizes[0] / DIN;
    int E = in_sizes[1] / 2;
    int NBK = (N + 255) >> 8;   // 196 coarse buckets

    char* ws = (char*)d_ws;
    size_t off = 0;
    auto carve = [&](size_t bytes) -> void* {
        void* p = ws + off;
        off = (off + bytes + 255) & ~(size_t)255;
        return p;
    };
    int*            bucketCnt = (int*)carve(256 * sizeof(int));
    int*            row_ptr   = (int*)carve((size_t)(N + 1) * sizeof(int));
    unsigned int*   part      = (unsigned int*)carve((size_t)NBK * CAPB * sizeof(unsigned int));
    unsigned short* srcs16    = (unsigned short*)carve((size_t)E * sizeof(unsigned short));
    _Float16*       Wh        = (_Float16*)carve(4 * 8192 * sizeof(_Float16));
    _Float16*       Qh        = (_Float16*)carve((size_t)N * HC * sizeof(_Float16));
    unsigned char*  KV8       = (unsigned char*)carve((size_t)N * 128);
    (void)ws_size; (void)n_in; (void)out_size;

    int qb = (N + TB - 1) / TB;          // GEMM blocks (782)
    int cb = (E + EPB - 1) / EPB;        // partition blocks (196)

    k_prep<<<128, 256, 0, stream>>>(Wq, Wk, Wv, Ws, Wh, bucketCnt);
    k_fused<<<qb + cb, 512, 0, stream>>>(
        (const float4*)x, Wh, bq, bk, bv, bs,
        Qh, KV8, out, N,
        ei, bucketCnt, part, E, cb);
    k_build<<<NBK, 1024, 0, stream>>>(part, bucketCnt, srcs16, row_ptr, N, NBK, E);
    k_attn<<<(N + 1) / 2, 128, 0, stream>>>(Qh, KV8, row_ptr, srcs16, out, N);
}

// Round 12
// 156.133 us; speedup vs baseline: 1.0435x; 1.0072x over previous
//
#include <hip/hip_runtime.h>
#include <hip/hip_bf16.h>

// N = 50000 nodes, E = 1.6M edges, D_IN = 128, H = 2 heads, C = 32 (HC=64).
// 4 dispatches (R23 = R22 + packed single-shfl attn V phase):
//   k_prep:  W fp32 -> f16 MFMA-B-frag layout; block 0 zeroes bucketCnt.
//   k_fused: 512-thread blocks. [blocks < cb] partition 8192 edges/block by
//            dst>>8 into padded bucket regions (int4 edge loads, rank-from-
//            histogram, wave-shfl scan; 128B part runs); [rest] ELU + 4
//            GEMMs via MFMA f16, TB=64, 8 waves. KV8 row layout: per-head
//            64B groups K_h[64h,64h+32) V_h[64h+32,64h+64).
//   k_build: ONE 1024-thread block per bucket: uint4 part reads, rank-from-
//            histogram counting sort in regs+LDS, coalesced dump.
//   k_attn:  wave-per-node softmax, 2 nodes per 128-thread block. V phase:
//            ex packed as f16 with sc in ONE shfl word (8 ds_bpermute per
//            chunk instead of 16; weights f16-RTN, denominator fp32 --
//            rounding noise well under fp8-V quantization).
// History: R10 L2-capacity => fp8 KV; R13 4B V gather; R14 batched V phase;
// R15 partition-first + rank-trick; R16 direct-atomic CSR REGRESSED 2x
// (write-allocate on random 2B stores); R17 1-block k_build; R18 TB=64
// GEMM; R19 fp8->f16 cvt NEUTRAL; R20 EPB 8192 + uint4 k_build (+12) but
// attn 512-blocks (-10); R21 revert attn blocks (157.8); R22 per-head KV
// grouping NEUTRAL (V gathers already latency-hidden). NOTE: dur_us
// includes ~88us of harness 256MiB fills (at HBM roofline, fixed);
// controllable kernel budget is ~69us.

#define DIN 128
#define HC  64
#define EPB 8192        // edges per partition block (mean run/bucket = 32 = 128B)
#define CAPB 12288      // padded bucket capacity (mean 8163, sigma ~90)

typedef _Float16 h2 __attribute__((ext_vector_type(2)));
typedef _Float16 h4 __attribute__((ext_vector_type(4)));
typedef _Float16 h8 __attribute__((ext_vector_type(8)));
typedef float    f4 __attribute__((ext_vector_type(4)));
typedef float    f2v __attribute__((ext_vector_type(2)));

#if defined(__has_builtin)
#if __has_builtin(__builtin_amdgcn_fdot2)
#define HAVE_FDOT2 1
#endif
#if __has_builtin(__builtin_amdgcn_cvt_pk_f16_fp8)
#define HAVE_PKF16FP8 1
#endif
#endif

static __device__ __forceinline__ float fdot2(h2 a, h2 b, float c) {
#ifdef HAVE_FDOT2
    return __builtin_amdgcn_fdot2(a, b, c, false);
#else
    return fmaf((float)a.x, (float)b.x, fmaf((float)a.y, (float)b.y, c));
#endif
}

// ---------------- prep: W fp32 -> f16 in MFMA B-fragment layout ----------------
__global__ __launch_bounds__(256) void k_prep(
        const float* __restrict__ Wq, const float* __restrict__ Wk,
        const float* __restrict__ Wv, const float* __restrict__ Ws,
        _Float16* __restrict__ Wh, int* __restrict__ bucketCnt) {
    int t = threadIdx.x;
    if (blockIdx.x == 0) bucketCnt[t] = 0;
    int idx = blockIdx.x * 256 + t;   // 0 .. 32767
    int m    = idx >> 13;
    int rem  = idx & 8191;
    int grp  = rem >> 9;          // ks*4 + nt
    int ks   = grp >> 2;
    int nt   = grp & 3;
    int r3   = rem & 511;
    int lane = r3 >> 3;
    int j    = r3 & 7;
    int k = ks * 32 + (lane >> 4) * 8 + j;
    int n = nt * 16 + (lane & 15);
    const float* W = (m == 0) ? Wq : (m == 1) ? Wk : (m == 2) ? Wv : Ws;
    Wh[idx] = (_Float16)W[k * 64 + n];
}

// ---------------- fused: edge partition (first) + MFMA GEMM (TB=64) ----------
#define TB 64
#define XS 136   // f16 stride per node row (128 + 8 pad)
__global__ __launch_bounds__(512) void k_fused(
        const float4* __restrict__ x4,
        const _Float16* __restrict__ Wh,
        const float* __restrict__ bq, const float* __restrict__ bk,
        const float* __restrict__ bv, const float* __restrict__ bs,
        _Float16* __restrict__ Q, unsigned char* __restrict__ KV8,
        float* __restrict__ OUT, int N,
        const int* __restrict__ ei, int* __restrict__ bucketCnt,
        unsigned int* __restrict__ part, int E, int cb) {
    __shared__ alignas(16) char smem[4096 + EPB * 4];   // 36.9 KB (GEMM uses 17.4)
    int t = threadIdx.x;
    int lane = t & 63, wid = t >> 6;

    if ((int)blockIdx.x < cb) {
        // ---------------- partition role (longest jobs -> dispatched first) ----
        int* hist  = (int*)smem;          // 256: counts (atomic rank source)
        int* lbase = hist + 256;          // 256: exclusive prefix
        int* gbase = lbase + 256;         // 256: global run base
        int* wsum  = gbase + 256;         // 4: wave sums for the scan
        unsigned int* stg = (unsigned int*)(smem + 4096);

        int e0 = (int)blockIdx.x * EPB;
        int cnt = min(EPB, E - e0);
        if (t < 256) hist[t] = 0;
        __syncthreads();

        // pass 1: pack + histogram; atomic return value IS the in-bucket rank.
        // Full blocks: int4 loads (4 edges each, 4 per thread).
        unsigned int pk[EPB / 512];
        unsigned short rk[EPB / 512];
        if (cnt == EPB) {
            const int4* s4 = (const int4*)(ei + e0);
            const int4* d4 = (const int4*)(ei + E + e0);
            #pragma unroll
            for (int u = 0; u < EPB / 2048; ++u) {
                int vi = t + u * 512;
                int4 sv = s4[vi];
                int4 dv = d4[vi];
                unsigned int* p = &pk[u * 4];
                p[0] = ((unsigned)dv.x << 16) | (unsigned)sv.x;
                p[1] = ((unsigned)dv.y << 16) | (unsigned)sv.y;
                p[2] = ((unsigned)dv.z << 16) | (unsigned)sv.z;
                p[3] = ((unsigned)dv.w << 16) | (unsigned)sv.w;
                #pragma unroll
                for (int q = 0; q < 4; ++q)
                    rk[u * 4 + q] = (unsigned short)atomicAdd(&hist[p[q] >> 24], 1);
            }
        } else {
            #pragma unroll
            for (int u = 0; u < EPB / 512; ++u) {
                int i = t + u * 512;
                if (i < cnt) {
                    unsigned int d = (unsigned int)ei[E + e0 + i];
                    unsigned int s = (unsigned int)ei[e0 + i];
                    pk[u] = (d << 16) | s;
                    rk[u] = (unsigned short)atomicAdd(&hist[d >> 8], 1);
                }
            }
        }
        __syncthreads();

        // 256-entry exclusive scan (waves 0-3) + bucket-region reservation
        if (t < 256) {
            int v = hist[t];
            int x = v;
            #pragma unroll
            for (int off = 1; off < 64; off <<= 1) {
                int y = __shfl_up(x, off, 64);
                if (lane >= off) x += y;
            }
            if (lane == 63) wsum[wid] = x;
            lbase[t] = x - v;             // wave-local exclusive part
        }
        __syncthreads();
        if (t < 256) {
            int wpre = 0;
            #pragma unroll
            for (int w = 0; w < 4; ++w) wpre += (w < wid) ? wsum[w] : 0;
            lbase[t] += wpre;
            int v = hist[t];
            if (v > 0) {
                int base = atomicAdd(&bucketCnt[t], v);
                base = min(base, CAPB - v);   // clamp: never cross bucket region
                gbase[t] = t * CAPB + base;
            }
        }
        __syncthreads();

        // scatter straight to LDS staging via rank (no second atomic pass)
        if (cnt == EPB) {
            #pragma unroll
            for (int u = 0; u < EPB / 512; ++u)
                stg[lbase[pk[u] >> 24] + (int)rk[u]] = pk[u];
        } else {
            #pragma unroll
            for (int u = 0; u < EPB / 512; ++u) {
                int i = t + u * 512;
                if (i < cnt) stg[lbase[pk[u] >> 24] + (int)rk[u]] = pk[u];
            }
        }
        __syncthreads();
        // contiguous dump per bucket run (mean 128B runs -> full-line writes)
        for (int i = t; i < cnt; i += 512) {
            unsigned int pkv = stg[i];
            int b = pkv >> 24;
            part[gbase[b] + (i - lbase[b])] = pkv;
        }
        return;
    }

    // ---------------- GEMM role (MFMA f16, 64 nodes/block, 8 waves) ----------
    _Float16* xs = (_Float16*)smem;   // [64][XS]
    int n0 = ((int)blockIdx.x - cb) * TB;

    #pragma unroll
    for (int u = 0; u < 4; ++u) {
        int idx = t + u * 512;        // 0..2047
        int row = idx >> 5;           // 0..63
        int k4  = idx & 31;
        int node = n0 + row;
        float4 v = make_float4(0.f, 0.f, 0.f, 0.f);
        if (node < N) v = x4[(size_t)node * 32 + k4];
        v.x = (v.x > 0.f) ? v.x : (__expf(v.x) - 1.0f);
        v.y = (v.y > 0.f) ? v.y : (__expf(v.y) - 1.0f);
        v.z = (v.z > 0.f) ? v.z : (__expf(v.z) - 1.0f);
        v.w = (v.w > 0.f) ? v.w : (__expf(v.w) - 1.0f);
        h4 hv = { (_Float16)v.x, (_Float16)v.y, (_Float16)v.z, (_Float16)v.w };
        *(h4*)&xs[row * XS + k4 * 4] = hv;
    }
    __syncthreads();

    int m    = wid >> 1;         // which matrix (wave-uniform)
    int half = wid & 1;          // row-half [0,2)
    int lr   = lane & 15;
    int lq   = lane >> 4;
    int r0   = half * 32;        // this wave's row base inside the tile

    const _Float16* Wm = Wh + m * 8192;
    const float* bias = (m == 0) ? bq : (m == 1) ? bk : (m == 2) ? bv : bs;

    f4 acc[2][4];
    #pragma unroll
    for (int mt = 0; mt < 2; ++mt)
        #pragma unroll
        for (int nt = 0; nt < 4; ++nt)
            acc[mt][nt] = (f4){0.f, 0.f, 0.f, 0.f};

    #pragma unroll
    for (int ks = 0; ks < 4; ++ks) {
        h8 a0 = *(const h8*)&xs[(r0 + lr) * XS + ks * 32 + lq * 8];
        h8 a1 = *(const h8*)&xs[(r0 + 16 + lr) * XS + ks * 32 + lq * 8];
        #pragma unroll
        for (int nt = 0; nt < 4; ++nt) {
            h8 b = *(const h8*)&Wm[((ks * 4 + nt) << 9) + lane * 8];
            acc[0][nt] = __builtin_amdgcn_mfma_f32_16x16x32_f16(a0, b, acc[0][nt], 0, 0, 0);
            acc[1][nt] = __builtin_amdgcn_mfma_f32_16x16x32_f16(a1, b, acc[1][nt], 0, 0, 0);
        }
    }

    // epilogue: D lane mapping col = lane&15, row = (lane>>4)*4 + reg
    // KV8 row layout: per-head 64B groups -- K_h[64h,64h+32), V_h[64h+32,64h+64)
    #pragma unroll
    for (int nt = 0; nt < 4; ++nt) {
        int col = nt * 16 + lr;
        float bb = bias[col];
        int head = col >> 5, chh = col & 31;
        int kvoff = (head << 6) + chh;           // K slot; +32 for V
        #pragma unroll
        for (int mt = 0; mt < 2; ++mt) {
            #pragma unroll
            for (int r = 0; r < 4; ++r) {
                int node = n0 + r0 + mt * 16 + lq * 4 + r;
                if (node < N) {
                    float val = acc[mt][nt][r] + bb;
                    if (m == 3) {
                        OUT[((size_t)node << 6) + col] = val;
                    } else if (m == 0) {
                        Q[((size_t)node << 6) + col] = (_Float16)val;
                    } else {
                        int pk8 = __builtin_amdgcn_cvt_pk_fp8_f32(val, val, 0, false);
                        KV8[((size_t)node << 7) + kvoff + ((m == 2) ? 32 : 0)] =
                            (unsigned char)(pk8 & 0xFF);
                    }
                }
            }
        }
    }
}

// ---------------- build: one 1024-thread block per bucket ----------------
// Counting sort of one bucket (<=CAPB edges): uint4 part reads (12 edges/
// thread in regs), rank-from-histogram, one 256-scan, LDS scatter,
// coalesced dump.
__global__ __launch_bounds__(1024) void k_build(
        const unsigned int* __restrict__ part, const int* __restrict__ bucketCnt,
        unsigned short* __restrict__ srcs16, int* __restrict__ row_ptr,
        int N, int NBK, int E) {
    __shared__ int hist[256], basep[256], wsum[4], sums[4];
    __shared__ unsigned short sbuf[CAPB];
    __shared__ int s_outBase, s_cnt;
    int t = threadIdx.x;          // 0..1023
    int b = blockIdx.x;           // bucket id
    int lane = t & 63, wid = t >> 6;

    // init hist + compute outBase (prefix over bucketCnt[0..b)) with waves 0-3
    if (t < 256) {
        hist[t] = 0;
        int c = (t < NBK && t < b) ? bucketCnt[t] : 0;
        #pragma unroll
        for (int off = 1; off < 64; off <<= 1) c += __shfl_xor(c, off, 64);
        if (lane == 0) sums[wid] = c;
    }
    if (t == 1023) s_cnt = min(bucketCnt[b], CAPB);
    __syncthreads();
    if (t == 0) s_outBase = sums[0] + sums[1] + sums[2] + sums[3];
    __syncthreads();
    int cnt = s_cnt;
    int outBase = s_outBase;
    int s0 = b * CAPB;

    // pass 1: read (uint4 main + scalar tail) + histogram; atomic return
    // value IS the within-dst rank
    unsigned int pk[CAPB / 1024];      // 12 slots
    int rk[CAPB / 1024];
    int cnt4 = cnt >> 2;               // full uint4 groups
    const uint4* p4 = (const uint4*)(part + s0);
    #pragma unroll
    for (int u = 0; u < CAPB / 4096; ++u) {   // 3 iterations
        int i4 = t + u * 1024;
        if (i4 < cnt4) {
            uint4 w = p4[i4];
            unsigned int* p = &pk[u * 4];
            p[0] = w.x; p[1] = w.y; p[2] = w.z; p[3] = w.w;
            #pragma unroll
            for (int q = 0; q < 4; ++q)
                rk[u * 4 + q] = atomicAdd(&hist[(p[q] >> 16) & 255], 1);
        }
    }
    unsigned int pkT = 0; int rkT = -1;
    {
        int j = (cnt4 << 2) + t;       // tail: at most 3 elements
        if (t < 4 && j < cnt) {
            pkT = part[s0 + j];
            rkT = atomicAdd(&hist[(pkT >> 16) & 255], 1);
        }
    }
    __syncthreads();

    // 256-entry exclusive scan of hist -> basep (waves 0-3)
    if (t < 256) {
        int v = hist[t];
        int x = v;
        #pragma unroll
        for (int off = 1; off < 64; off <<= 1) {
            int y = __shfl_up(x, off, 64);
            if (lane >= off) x += y;
        }
        if (lane == 63) wsum[wid] = x;
        basep[t] = x - v;   // wave-local exclusive; add wave prefix after barrier
    }
    __syncthreads();
    if (t < 256) {
        int wpre = 0;
        #pragma unroll
        for (int w = 0; w < 4; ++w) wpre += (w < wid) ? wsum[w] : 0;
        basep[t] += wpre;
    }
    __syncthreads();

    // scatter into LDS staging at final within-bucket position
    #pragma unroll
    for (int u = 0; u < CAPB / 4096; ++u) {
        int i4 = t + u * 1024;
        if (i4 < cnt4) {
            #pragma unroll
            for (int q = 0; q < 4; ++q) {
                unsigned int pkv = pk[u * 4 + q];
                int d = (pkv >> 16) & 255;
                int pos = basep[d] + rk[u * 4 + q];
                if (pos < CAPB) sbuf[pos] = (unsigned short)(pkv & 0xFFFFu);
            }
        }
    }
    if (rkT >= 0) {
        int d = (pkT >> 16) & 255;
        int pos = basep[d] + rkT;
        if (pos < CAPB) sbuf[pos] = (unsigned short)(pkT & 0xFFFFu);
    }
    __syncthreads();

    // coalesced dump + row_ptr
    for (int i = t; i < cnt; i += 1024)
        srcs16[outBase + i] = sbuf[i];
    if (t < 256) {
        int node = (b << 8) + t;
        if (node < N) row_ptr[node] = outBase + basep[t];
    }
    if (b == 0 && t == 1023) row_ptr[N] = E;
}

// ---------------- per-node softmax attention (fp8 per-head 64B KV) ----------------
// One wave per dst node, 2 nodes per 128-thread block. Alpha: lane (head
// h5 = lane&32, c = lane&31) does edge c's 32-dim dot in-lane; 4 partial
// chains. KV row layout: K_h[64h,64h+32) V_h[64h+32,64h+64). Cross-chunk
// pipeline: srcs prefetched 1 chunk ahead; next chunk's K loads issued
// before the V phase. V phase (R23): ex packed as f16 alongside sc in one
// 32-bit word -> ONE shfl per edge-group (8 ds_bpermute/chunk, was 16);
// weights f16-RTN (denominator stays fp32; rounding noise << fp8-V quant).
__global__ __launch_bounds__(128) void k_attn(
        const _Float16* __restrict__ Q, const unsigned char* __restrict__ KV8,
        const int* __restrict__ row_ptr,
        const unsigned short* __restrict__ srcs16, float* __restrict__ out, int N) {
    int lane = threadIdx.x & 63;
    int wave = threadIdx.x >> 6;
    int n = blockIdx.x * 2 + wave;
    if (n >= N) return;
    int h5 = lane & 32;            // head selector (alpha half AND channel head)
    int c  = lane & 31;
    int eg = (lane >> 3) & 3;      // V-phase edge slot [0,4)
    int ch = lane & 7;             // V-phase 4B channel chunk [0,8)

    int start = row_ptr[n];
    int deg   = row_ptr[n + 1] - start;
    if (deg <= 0) return;          // out already holds the skip term

    h8 q8[4];
    {
        const h8* qp = (const h8*)(Q + ((size_t)n << 6) + h5);
        #pragma unroll
        for (int r = 0; r < 4; ++r) q8[r] = qp[r];
    }
    const h2* q2 = (const h2*)q8;  // 16 channel pairs

    const float scale = 0.17677669529663687f;  // 1/sqrt(32)
    float lsum = 0.f;
    f4 acc = (f4){0.f, 0.f, 0.f, 0.f};

    // per-head 64B group base: head h at byte 64h; V at +32
    unsigned kbase = (unsigned)(h5 << 1);            // 0 or 64
    unsigned vofs  = kbase + 32u + ((unsigned)ch << 2);

    // pipeline prologue: chunk 0's src + K loads
    int sc_cur = (c < deg) ? (int)srcs16[start + c] : 0;
    uint4 ka, kb;
    {
        unsigned ko = ((unsigned)sc_cur << 7) + kbase;
        ka = *(const uint4*)(KV8 + ko);
        kb = *(const uint4*)(KV8 + ko + 16);
    }

    for (int i0 = 0; i0 < deg; i0 += 32) {
        int nb = min(32, deg - i0);
        int sc = sc_cur;
        int i1 = i0 + 32;

        // prefetch next chunk's src indices
        int sc_next = 0;
        if (i1 < deg && c < deg - i1) sc_next = (int)srcs16[start + i1 + c];

        // dot for this chunk (consumes ka/kb); 4 partial chains
        float s0 = 0.f, s1 = 0.f, s2 = 0.f, s3 = 0.f;
#ifdef HAVE_PKF16FP8
#define KDOT(kw, idx, ss) { \
        h2 p01 = __builtin_amdgcn_cvt_pk_f16_fp8((short)((kw) & 0xFFFFu)); \
        h2 p23 = __builtin_amdgcn_cvt_pk_f16_fp8((short)((kw) >> 16)); \
        ss = fdot2(p01, q2[2*(idx)],   ss); \
        ss = fdot2(p23, q2[2*(idx)+1], ss); }
#else
#define KDOT(kw, idx, ss) { \
        f2v f01 = __builtin_amdgcn_cvt_pk_f32_fp8((int)(kw), false); \
        f2v f23 = __builtin_amdgcn_cvt_pk_f32_fp8((int)(kw), true);  \
        auto p01 = __builtin_amdgcn_cvt_pkrtz(f01[0], f01[1]); \
        auto p23 = __builtin_amdgcn_cvt_pkrtz(f23[0], f23[1]); \
        ss = fdot2(*(h2*)&p01, q2[2*(idx)],   ss); \
        ss = fdot2(*(h2*)&p23, q2[2*(idx)+1], ss); }
#endif
        KDOT(ka.x, 0, s0) KDOT(ka.y, 1, s1) KDOT(ka.z, 2, s2) KDOT(ka.w, 3, s3)
        KDOT(kb.x, 4, s0) KDOT(kb.y, 5, s1) KDOT(kb.z, 6, s2) KDOT(kb.w, 7, s3)
#undef KDOT
        float s = (s0 + s1) + (s2 + s3);
        float ex = (c < nb) ? __expf(s * scale) : 0.f;
        lsum += ex;

        // pack ex (f16 RTN, exactly 0 for padding lanes) with src id:
        // one shfl word carries both weight and row for the V phase
        _Float16 exh = (_Float16)ex;
        unsigned packed = ((unsigned)sc << 16) |
                          (unsigned)*(unsigned short*)&exh;

        // issue next chunk's K loads now; they fly during the V phase
        if (i1 < deg) {
            unsigned ko = ((unsigned)sc_next << 7) + kbase;
            ka = *(const uint4*)(KV8 + ko);
            kb = *(const uint4*)(KV8 + ko + 16);
        }
        sc_cur = sc_next;

        // ---- batched V phase: fixed 8 groups of 4 edges, ONE shfl each ----
        float wv[8]; unsigned sj[8];
        #pragma unroll
        for (int u = 0; u < 8; ++u) {
            int j = 4 * u + eg;
            unsigned pw = (unsigned)__shfl((int)packed, h5 + j, 64);
            sj[u] = pw >> 16;
            unsigned short wb = (unsigned short)(pw & 0xFFFFu);
            wv[u] = (float)*(_Float16*)&wb;      // 0 beyond nb (f16(0)==0)
        }
        unsigned vw[8];
        #pragma unroll
        for (int u = 0; u < 8; ++u)
            vw[u] = *(const unsigned int*)(KV8 + ((sj[u] << 7) + vofs));
        #pragma unroll
        for (int u = 0; u < 8; ++u) {
            f2v v01 = __builtin_amdgcn_cvt_pk_f32_fp8((int)vw[u], false);
            f2v v23 = __builtin_amdgcn_cvt_pk_f32_fp8((int)vw[u], true);
            acc[0] = fmaf(wv[u], v01[0], acc[0]);
            acc[1] = fmaf(wv[u], v01[1], acc[1]);
            acc[2] = fmaf(wv[u], v23[0], acc[2]);
            acc[3] = fmaf(wv[u], v23[1], acc[3]);
        }
    }

    // fold edge slots (lanes ^8 and ^16 share my channel chunk)
    #pragma unroll
    for (int i = 0; i < 4; ++i) {
        acc[i] += __shfl_xor(acc[i], 8, 64);
        acc[i] += __shfl_xor(acc[i], 16, 64);
    }

    // per-head denominator (reduce within my half)
    float ls = lsum;
    ls += __shfl_xor(ls, 16, 64);
    ls += __shfl_xor(ls,  8, 64);
    ls += __shfl_xor(ls,  4, 64);
    ls += __shfl_xor(ls,  2, 64);
    ls += __shfl_xor(ls,  1, 64);
    float rden = 1.0f / fmaxf(ls, 1e-16f);

    if ((lane & 24) == 0) {  // lanes 0-7 (head 0) and 32-39 (head 1)
        float4* o4 = (float4*)out + ((size_t)n << 4) + (h5 >> 2) + ch;
        float4 cur4 = *o4;
        cur4.x += acc[0] * rden;
        cur4.y += acc[1] * rden;
        cur4.z += acc[2] * rden;
        cur4.w += acc[3] * rden;
        *o4 = cur4;
    }
}

// ---------------- launch ----------------
extern "C" void kernel_launch(void* const* d_in, const int* in_sizes, int n_in,
                              void* d_out, int out_size, void* d_ws, size_t ws_size,
                              hipStream_t stream) {
    const float* x  = (const float*)d_in[0];
    const int*   ei = (const int*)d_in[1];
    const float* Wq = (const float*)d_in[2];
    const float* bq = (const float*)d_in[3];
    const float* Wk = (const float*)d_in[4];
    const float* bk = (const float*)d_in[5];
    const float* Wv = (const float*)d_in[6];
    const float* bv = (const float*)d_in[7];
    const float* Ws = (const float*)d_in[8];
    const float* bs = (const float*)d_in[9];
    float* out = (float*)d_out;

    int N = in_sizes[0] / DIN;
    int E = in_sizes[1] / 2;
    int NBK = (N + 255) >> 8;   // 196 coarse buckets

    char* ws = (char*)d_ws;
    size_t off = 0;
    auto carve = [&](size_t bytes) -> void* {
        void* p = ws + off;
        off = (off + bytes + 255) & ~(size_t)255;
        return p;
    };
    int*            bucketCnt = (int*)carve(256 * sizeof(int));
    int*            row_ptr   = (int*)carve((size_t)(N + 1) * sizeof(int));
    unsigned int*   part      = (unsigned int*)carve((size_t)NBK * CAPB * sizeof(unsigned int));
    unsigned short* srcs16    = (unsigned short*)carve((size_t)E * sizeof(unsigned short));
    _Float16*       Wh        = (_Float16*)carve(4 * 8192 * sizeof(_Float16));
    _Float16*       Qh        = (_Float16*)carve((size_t)N * HC * sizeof(_Float16));
    unsigned char*  KV8       = (unsigned char*)carve((size_t)N * 128);
    (void)ws_size; (void)n_in; (void)out_size;

    int qb = (N + TB - 1) / TB;          // GEMM blocks (782)
    int cb = (E + EPB - 1) / EPB;        // partition blocks (196)

    k_prep<<<128, 256, 0, stream>>>(Wq, Wk, Wv, Ws, Wh, bucketCnt);
    k_fused<<<qb + cb, 512, 0, stream>>>(
        (const float4*)x, Wh, bq, bk, bv, bs,
        Qh, KV8, out, N,
        ei, bucketCnt, part, E, cb);
    k_build<<<NBK, 1024, 0, stream>>>(part, bucketCnt, srcs16, row_ptr, N, NBK, E);
    k_attn<<<(N + 1) / 2, 128, 0, stream>>>(Qh, KV8, row_ptr, srcs16, out, N);
}